// Round 13
// baseline (647.685 us; speedup 1.0000x reference)
//
#include <hip/hip_runtime.h>

typedef __bf16 bf16_t;
typedef __bf16 bf16x8 __attribute__((ext_vector_type(8)));
typedef float f32x4 __attribute__((ext_vector_type(4)));

#define LN_EPS 1e-3f

__device__ __forceinline__ void gload_lds16(const void* g, void* l) {
    __builtin_amdgcn_global_load_lds(
        (__attribute__((address_space(1))) void*)(g),
        (__attribute__((address_space(3))) void*)(l), 16, 0, 0);
}

// ---------------- weight prep (LDS-tiled, coalesced both sides) ----------------
__global__ __launch_bounds__(256)
void transpose_f32_bf16(const float* __restrict__ in, bf16_t* __restrict__ outp,
                        int ldi, int ldo)
{
    __shared__ float tile[64][65];
    const int k0 = blockIdx.x * 64, n0 = blockIdx.y * 64;
    const int tid = threadIdx.x;
    const int r = tid >> 2;
    const int q = tid & 3;
    const float* src = in + (long)(k0 + r) * ldi + n0 + q * 16;
#pragma unroll
    for (int j = 0; j < 4; ++j) {
        float4 v = *(const float4*)(src + j * 4);
        tile[r][q * 16 + j * 4 + 0] = v.x;
        tile[r][q * 16 + j * 4 + 1] = v.y;
        tile[r][q * 16 + j * 4 + 2] = v.z;
        tile[r][q * 16 + j * 4 + 3] = v.w;
    }
    __syncthreads();
    union { bf16_t e[16]; uint4 u[2]; } pk;
#pragma unroll
    for (int j = 0; j < 16; ++j) pk.e[j] = (bf16_t)tile[q * 16 + j][r];
    bf16_t* dst = outp + (long)(n0 + r) * ldo + k0 + q * 16;
    *(uint4*)(dst)     = pk.u[0];
    *(uint4*)(dst + 8) = pk.u[1];
}

__global__ __launch_bounds__(256)
void pack_qkv_t(const float* __restrict__ wq, const float* __restrict__ wk,
                const float* __restrict__ wv, bf16_t* __restrict__ outp)
{
    __shared__ float tile[64][65];
    const int m   = blockIdx.y;           // 0..47
    const int sel = m >> 4, h = m & 15;
    const float* in = ((sel == 0) ? wq : (sel == 1) ? wk : wv) + (long)h * 65536;
    bf16_t* out = outp + ((long)sel * 1024 + h * 64) * 1024;
    const int k0 = blockIdx.x * 64;
    const int tid = threadIdx.x;
    const int r = tid >> 2;
    const int q = tid & 3;
    const float* src = in + (long)(k0 + r) * 64 + q * 16;
#pragma unroll
    for (int j = 0; j < 4; ++j) {
        float4 v = *(const float4*)(src + j * 4);
        tile[r][q * 16 + j * 4 + 0] = v.x;
        tile[r][q * 16 + j * 4 + 1] = v.y;
        tile[r][q * 16 + j * 4 + 2] = v.z;
        tile[r][q * 16 + j * 4 + 3] = v.w;
    }
    __syncthreads();
    union { bf16_t e[16]; uint4 u[2]; } pk;
#pragma unroll
    for (int j = 0; j < 16; ++j) pk.e[j] = (bf16_t)tile[q * 16 + j][r];
    bf16_t* dst = out + (long)r * 1024 + k0 + q * 16;
    *(uint4*)(dst)     = pk.u[0];
    *(uint4*)(dst + 8) = pk.u[1];
}

// ---------------- layernorm (f32 in -> bf16 LN out) ----------------
__global__ __launch_bounds__(256)
void ln_fwd(const float* __restrict__ in, const float* __restrict__ g,
            const float* __restrict__ be, bf16_t* __restrict__ outp)
{
    const long row = blockIdx.x;
    const int t = threadIdx.x;
    float4 v = ((const float4*)(in + row * 1024))[t];
    float s  = v.x + v.y + v.z + v.w;
    float sq = v.x * v.x + v.y * v.y + v.z * v.z + v.w * v.w;
#pragma unroll
    for (int off = 1; off < 64; off <<= 1) {
        s  += __shfl_xor(s, off);
        sq += __shfl_xor(sq, off);
    }
    __shared__ float red[8];
    if ((t & 63) == 0) { red[(t >> 6) * 2] = s; red[(t >> 6) * 2 + 1] = sq; }
    __syncthreads();
    s  = red[0] + red[2] + red[4] + red[6];
    sq = red[1] + red[3] + red[5] + red[7];
    float mean = s * 0.0009765625f;
    float var  = sq * 0.0009765625f - mean * mean;
    float rstd = rsqrtf(var + LN_EPS);
    float4 gv = ((const float4*)g)[t];
    float4 bv = ((const float4*)be)[t];
    union { bf16_t h[4]; uint2 u; } pk;
    pk.h[0] = (bf16_t)((v.x - mean) * rstd * gv.x + bv.x);
    pk.h[1] = (bf16_t)((v.y - mean) * rstd * gv.y + bv.y);
    pk.h[2] = (bf16_t)((v.z - mean) * rstd * gv.z + bv.z);
    pk.h[3] = (bf16_t)((v.w - mean) * rstd * gv.w + bv.w);
    *(uint2*)(outp + row * 1024 + t * 4) = pk.u;
}

// ---------------- final layernorm (bf16 in + f32 res -> f32 out) ----------------
__global__ __launch_bounds__(256)
void ln3_kernel(const bf16_t* __restrict__ in, const float* __restrict__ g,
                const float* __restrict__ be, float* outp, const float* res)
{
    const long row = blockIdx.x;
    const int t = threadIdx.x;
    union { uint2 u; bf16_t h[4]; } pk;
    pk.u = *(const uint2*)(in + row * 1024 + t * 4);
    float v0 = (float)pk.h[0], v1 = (float)pk.h[1], v2 = (float)pk.h[2], v3 = (float)pk.h[3];
    float s  = v0 + v1 + v2 + v3;
    float sq = v0 * v0 + v1 * v1 + v2 * v2 + v3 * v3;
#pragma unroll
    for (int off = 1; off < 64; off <<= 1) {
        s  += __shfl_xor(s, off);
        sq += __shfl_xor(sq, off);
    }
    __shared__ float red[8];
    if ((t & 63) == 0) { red[(t >> 6) * 2] = s; red[(t >> 6) * 2 + 1] = sq; }
    __syncthreads();
    s  = red[0] + red[2] + red[4] + red[6];
    sq = red[1] + red[3] + red[5] + red[7];
    float mean = s * 0.0009765625f;
    float var  = sq * 0.0009765625f - mean * mean;
    float rstd = rsqrtf(var + LN_EPS);
    float4 gv = ((const float4*)g)[t];
    float4 bv = ((const float4*)be)[t];
    float4 rv = ((const float4*)(res + row * 1024))[t];
    float4 ov;
    ov.x = rv.x + (v0 - mean) * rstd * gv.x + bv.x;
    ov.y = rv.y + (v1 - mean) * rstd * gv.y + bv.y;
    ov.z = rv.z + (v2 - mean) * rstd * gv.z + bv.z;
    ov.w = rv.w + (v3 - mean) * rstd * gv.w + bv.w;
    ((float4*)outp)[row * 256 + t] = ov;
}

// ---------------- GEMM: C[M,N] = A[M,K] * Bt[N,K]^T ----------------
// 256x256 tile, BK=64, 512 threads = 8 waves; 4 phases/K-tile.
// Deep pipeline both operands: A 3-buf staged 2 tiles ahead (P1 h0, P3 h1 of
// iter c -> A(c+2)); B 2-buf staged at P3 of iter c -> B(c+2) into the buffer
// whose reads finished at P2's end barrier. Covers: A 7 phases, B 6 phases
// (~1200cy > HBM 900cy). P4 vmcnt(8): queue = A(c+1)4 + B(c+1)4 + A(c+2)4 +
// B(c+2)4 = 16 -> drains c+1 tiles exactly, leaves c+2 in flight.
// Prologue stages tiles 0,1 of A and B, vmcnt(0). LDS = 5x32KB = 160KB.
// MODE 0: bf16=acc; 1: f32=acc+bias+addf32; 2: bf16=relu(acc+bias);
// MODE 3: bf16=acc+bias+(float)addbf16 (outp may == addp);
// MODE 4: QKV mode — cols<2048 bf16=acc to outp; cols>=2048 (V) write V^T into
//         addp as vt[((b*16+h)*64+d)*256 + s] (packed 4-row uint2 stores).
template<int MODE>
__global__ __launch_bounds__(512, 2)
void gemm_bt(const bf16_t* __restrict__ Ap, const bf16_t* __restrict__ Bp,
             void* outp, const float* __restrict__ bias,
             const void* addp, int M, int N, int K)
{
    __shared__ __attribute__((aligned(16))) bf16_t As0[256 * 64];
    __shared__ __attribute__((aligned(16))) bf16_t As1[256 * 64];
    __shared__ __attribute__((aligned(16))) bf16_t As2[256 * 64];
    __shared__ __attribute__((aligned(16))) bf16_t Bs0[256 * 64];
    __shared__ __attribute__((aligned(16))) bf16_t Bs1[256 * 64];

    const int tid  = threadIdx.x;
    const int w    = tid >> 6, lane = tid & 63;
    const int l16  = lane & 15, lg = lane >> 4;
    const int wm   = w >> 2, wn = w & 3;
    const int srow = lane >> 3;
    const int sslot = lane & 7;

    const int gx  = gridDim.x;
    const int gy  = gridDim.y;
    const int nwg = gx * gy;
    const int bid = blockIdx.y * gx + blockIdx.x;
    const int cpx = nwg >> 3;
    const int sid = (bid & 7) * cpx + (bid >> 3);
    const long m0 = (long)(sid / gy) * 256;
    const long n0 = (long)(sid % gy) * 256;
    const int nkt = K >> 6;

    f32x4 acc[8][4] = {};
    bf16x8 a[4][2], b0[2][2], b1[2][2];

    auto STAGEH = [&](const bf16_t* src, long row0, int kt, bf16_t* dst, int h) {
#pragma unroll
        for (int i = 0; i < 2; ++i) {
            int r  = h * 128 + w * 16 + i * 8 + srow;
            int ss = sslot ^ (r & 7);
            gload_lds16(src + (row0 + r) * (long)K + (long)kt * 64 + ss * 8,
                        dst + (h * 128 + w * 16 + i * 8) * 64);
        }
    };

#define LDA_M(buf, mh) do {                                               \
    _Pragma("unroll") for (int j = 0; j < 4; ++j)                         \
    _Pragma("unroll") for (int kk = 0; kk < 2; ++kk) {                    \
        int r  = wm * 128 + (mh) * 64 + j * 16 + l16;                     \
        int ss = (kk * 4 + lg) ^ (r & 7);                                 \
        a[j][kk] = *(const bf16x8*)&buf[r * 64 + ss * 8];                 \
    } } while (0)

#define LDB_M(dst, buf, nh) do {                                          \
    _Pragma("unroll") for (int n = 0; n < 2; ++n)                         \
    _Pragma("unroll") for (int kk = 0; kk < 2; ++kk) {                    \
        int r  = wn * 64 + ((nh) * 2 + n) * 16 + l16;                     \
        int ss = (kk * 4 + lg) ^ (r & 7);                                 \
        dst[n][kk] = *(const bf16x8*)&buf[r * 64 + ss * 8];               \
    } } while (0)

#define MMA_M(bv, mh, nh) do {                                            \
    __builtin_amdgcn_s_setprio(1);                                        \
    _Pragma("unroll") for (int j = 0; j < 4; ++j)                         \
    _Pragma("unroll") for (int n = 0; n < 2; ++n)                         \
    _Pragma("unroll") for (int kk = 0; kk < 2; ++kk)                      \
        acc[(mh) * 4 + j][(nh) * 2 + n] =                                 \
            __builtin_amdgcn_mfma_f32_16x16x32_bf16(                      \
                a[j][kk], bv[n][kk], acc[(mh) * 4 + j][(nh) * 2 + n],     \
                0, 0, 0);                                                 \
    __builtin_amdgcn_s_setprio(0);                                        \
} while (0)

#define PRE_MFMA() do { __builtin_amdgcn_s_barrier();                     \
    asm volatile("s_waitcnt lgkmcnt(0)" ::: "memory");                    \
    __builtin_amdgcn_sched_barrier(0); } while (0)

    // ---- prologue: A(0),B(0),A(1),B(1) all staged and landed ----
    STAGEH(Ap, m0, 0, As0, 0); STAGEH(Ap, m0, 0, As0, 1);
    STAGEH(Bp, n0, 0, Bs0, 0); STAGEH(Bp, n0, 0, Bs0, 1);
    if (nkt > 1) {
        STAGEH(Ap, m0, 1, As1, 0); STAGEH(Ap, m0, 1, As1, 1);
        STAGEH(Bp, n0, 1, Bs1, 0); STAGEH(Bp, n0, 1, Bs1, 1);
    }
    asm volatile("s_waitcnt vmcnt(0)" ::: "memory");
    __builtin_amdgcn_s_barrier();
    __builtin_amdgcn_sched_barrier(0);

    bf16_t *Ar = As0, *An1 = As1, *An2 = As2;
    bf16_t *Br = Bs0, *Bw = Bs1;

    for (int c = 0; c < nkt; ++c) {
        const bool pf = (c + 2 < nkt);

        // P1
        LDA_M(Ar, 0); LDB_M(b0, Br, 0);
        if (pf) STAGEH(Ap, m0, c + 2, An2, 0);
        PRE_MFMA(); MMA_M(b0, 0, 0); __builtin_amdgcn_s_barrier();
        // P2
        LDB_M(b1, Br, 1);
        PRE_MFMA(); MMA_M(b1, 0, 1); __builtin_amdgcn_s_barrier();
        // P3  (Br reads finished at P2's end barrier -> safe to overwrite)
        LDA_M(Ar, 1);
        if (pf) {
            STAGEH(Ap, m0, c + 2, An2, 1);
            STAGEH(Bp, n0, c + 2, Br, 0); STAGEH(Bp, n0, c + 2, Br, 1);
        }
        PRE_MFMA(); MMA_M(b1, 1, 1); __builtin_amdgcn_s_barrier();
        // P4
        if (pf) { asm volatile("s_waitcnt vmcnt(8)" ::: "memory"); }
        else    { asm volatile("s_waitcnt vmcnt(0)" ::: "memory"); }
        __builtin_amdgcn_s_barrier();
        __builtin_amdgcn_sched_barrier(0);
        MMA_M(b0, 1, 0); __builtin_amdgcn_s_barrier();

        bf16_t* t = Ar; Ar = An1; An1 = An2; An2 = t;
        t = Br; Br = Bw; Bw = t;
    }

    // ---- epilogue ----
#pragma unroll
    for (int fm = 0; fm < 8; ++fm) {
#pragma unroll
        for (int fn = 0; fn < 4; ++fn) {
            const long gcol = n0 + wn * 64 + fn * 16 + l16;
            float bv = 0.f;
            if (MODE != 0 && MODE != 4) bv = bias[gcol];
            const long grow0 = m0 + wm * 128 + fm * 16 + lg * 4;
            if (MODE == 4 && gcol >= 2048) {
                union { bf16_t h[4]; uint2 u; } pk;
#pragma unroll
                for (int e = 0; e < 4; ++e) pk.h[e] = (bf16_t)acc[fm][fn][e];
                const int hh = (int)(gcol >> 6) - 32;
                const int d  = (int)gcol & 63;
                const long bb = grow0 >> 8;
                const int s0  = (int)grow0 & 255;
                *(uint2*)((bf16_t*)addp + ((bb * 16 + hh) * 64 + d) * 256 + s0) = pk.u;
                continue;
            }
#pragma unroll
            for (int e = 0; e < 4; ++e) {
                const long grow = grow0 + e;
                float v = acc[fm][fn][e];
                if (MODE == 0 || MODE == 4) {
                    ((bf16_t*)outp)[grow * N + gcol] = (bf16_t)v;
                } else if (MODE == 1) {
                    v += bv + ((const float*)addp)[grow * N + gcol];
                    ((float*)outp)[grow * N + gcol] = v;
                } else if (MODE == 2) {
                    v += bv; v = v > 0.f ? v : 0.f;
                    ((bf16_t*)outp)[grow * N + gcol] = (bf16_t)v;
                } else {
                    v += bv + (float)((const bf16_t*)addp)[grow * N + gcol];
                    ((bf16_t*)outp)[grow * N + gcol] = (bf16_t)v;
                }
            }
        }
    }
#undef LDA_M
#undef LDB_M
#undef MMA_M
#undef PRE_MFMA
}

// ---------------- fused causal attention ----------------
// qkv: [B*T, 3072] bf16 (Q cols 0..1023, K cols 1024..2047)
// vt:  [B*H, 64, 256] bf16 (V^T, written by QKV GEMM MODE 4)
// 1 block per (b,h); 4 waves. One-shot staging: all 4 K/V tiles (64KB) staged
// once, single vmcnt(0)+barrier, then the causal triangle runs barrier-free
// (Ps is per-wave). Causal-balanced: fm block owns rows fm*64 + w*16 + [0,16).
// LDS 73KB -> 2 blocks/CU.
__global__ __launch_bounds__(256)
void attn_kernel(const bf16_t* __restrict__ qkv, const bf16_t* __restrict__ vt,
                 bf16_t* __restrict__ outp)
{
    __shared__ __attribute__((aligned(16))) bf16_t Kt[4][64 * 64];
    __shared__ __attribute__((aligned(16))) bf16_t Vt[4][64 * 64];
    __shared__ __attribute__((aligned(16))) bf16_t Ps[4][16 * 72];

    const int tid = threadIdx.x, w = tid >> 6, lane = tid & 63;
    const int l16 = lane & 15, lg = lane >> 4;
    const int b = blockIdx.x >> 4, hh = blockIdx.x & 15;
    const bf16_t* pq = qkv + (long)(b * 256) * 3072 + hh * 64;
    const bf16_t* pv = vt + (long)blockIdx.x * 64 * 256;
    const int sr8 = lane >> 3;
    const int sl  = lane & 7;

    // Q fragments: fm block rows = fm*64 + w*16 + l16
    bf16x8 qf[4][2];
#pragma unroll
    for (int fm = 0; fm < 4; ++fm)
#pragma unroll
        for (int kk = 0; kk < 2; ++kk)
            qf[fm][kk] = *(const bf16x8*)(pq + (long)(fm * 64 + w * 16 + l16) * 3072
                                          + kk * 32 + lg * 8);

    // one-shot stage of all K and V tiles
#pragma unroll
    for (int st = 0; st < 4; ++st)
#pragma unroll
        for (int i = 0; i < 2; ++i) {
            int r  = w * 16 + i * 8 + sr8;
            int ss = sl ^ (r & 7);
            gload_lds16(pq + (long)(st * 64 + r) * 3072 + 1024 + ss * 8,
                        &Kt[st][(w * 16 + i * 8) * 64]);
            gload_lds16(pv + (long)r * 256 + st * 64 + ss * 8,
                        &Vt[st][(w * 16 + i * 8) * 64]);
        }
    asm volatile("s_waitcnt vmcnt(0)" ::: "memory");
    __syncthreads();

    f32x4 o[4][4] = {};
    float mrun[4][4], lrun[4][4];
#pragma unroll
    for (int i = 0; i < 4; ++i)
#pragma unroll
        for (int j = 0; j < 4; ++j) { mrun[i][j] = -__builtin_inff(); lrun[i][j] = 0.f; }

#pragma unroll
    for (int st = 0; st < 4; ++st) {
        // S = Q K^T for fm >= st
        f32x4 s[4][4] = {};
#pragma unroll
        for (int ks = 0; ks < 2; ++ks) {
            bf16x8 kb[4];
#pragma unroll
            for (int fs = 0; fs < 4; ++fs)
                kb[fs] = *(const bf16x8*)&Kt[st][(fs * 16 + l16) * 64
                                                + ((ks * 4 + lg) ^ (l16 & 7)) * 8];
#pragma unroll
            for (int fm = 0; fm < 4; ++fm) {
                if (fm < st) continue;
#pragma unroll
                for (int fs = 0; fs < 4; ++fs)
                    s[fm][fs] = __builtin_amdgcn_mfma_f32_16x16x32_bf16(
                        qf[fm][ks], kb[fs], s[fm][fs], 0, 0, 0);
            }
        }

#pragma unroll
        for (int fm = 0; fm < 4; ++fm) {
            if (fm < st) continue;
#pragma unroll
            for (int fs = 0; fs < 4; ++fs)
#pragma unroll
                for (int e = 0; e < 4; ++e) {
                    float v = s[fm][fs][e] * 0.03125f;
                    if (st == fm && (fs * 16 + l16) > (w * 16 + lg * 4 + e))
                        v = -__builtin_inff();
                    s[fm][fs][e] = v;
                }
#pragma unroll
            for (int e = 0; e < 4; ++e) {
                float pm = fmaxf(fmaxf(s[fm][0][e], s[fm][1][e]),
                                 fmaxf(s[fm][2][e], s[fm][3][e]));
#pragma unroll
                for (int off = 1; off < 16; off <<= 1) pm = fmaxf(pm, __shfl_xor(pm, off));
                float mnew  = fmaxf(mrun[fm][e], pm);
                float alpha = __expf(mrun[fm][e] - mnew);
                float rs = 0.f;
#pragma unroll
                for (int fs = 0; fs < 4; ++fs) {
                    float p = __expf(s[fm][fs][e] - mnew);
                    s[fm][fs][e] = p;
                    rs += p;
                }
#pragma unroll
                for (int off = 1; off < 16; off <<= 1) rs += __shfl_xor(rs, off);
                lrun[fm][e] = lrun[fm][e] * alpha + rs;
                mrun[fm][e] = mnew;
#pragma unroll
                for (int fd = 0; fd < 4; ++fd) o[fm][fd][e] *= alpha;
            }
#pragma unroll
            for (int fs = 0; fs < 4; ++fs)
#pragma unroll
                for (int e = 0; e < 4; ++e)
                    Ps[w][(lg * 4 + e) * 72 + fs * 16 + l16] = (bf16_t)s[fm][fs][e];
            bf16x8 ap0 = *(const bf16x8*)&Ps[w][l16 * 72 + lg * 8];
            bf16x8 ap1 = *(const bf16x8*)&Ps[w][l16 * 72 + 32 + lg * 8];
#pragma unroll
            for (int fd = 0; fd < 4; ++fd) {
                bf16x8 vb0 = *(const bf16x8*)&Vt[st][(fd * 16 + l16) * 64
                                                    + ((lg) ^ (l16 & 7)) * 8];
                bf16x8 vb1 = *(const bf16x8*)&Vt[st][(fd * 16 + l16) * 64
                                                    + ((4 + lg) ^ (l16 & 7)) * 8];
                o[fm][fd] = __builtin_amdgcn_mfma_f32_16x16x32_bf16(ap0, vb0, o[fm][fd], 0, 0, 0);
                o[fm][fd] = __builtin_amdgcn_mfma_f32_16x16x32_bf16(ap1, vb1, o[fm][fd], 0, 0, 0);
            }
        }
    }

#pragma unroll
    for (int fm = 0; fm < 4; ++fm)
#pragma unroll
        for (int e = 0; e < 4; ++e) {
            float inv = 1.f / lrun[fm][e];
            long row = (long)b * 256 + fm * 64 + w * 16 + lg * 4 + e;
#pragma unroll
            for (int fd = 0; fd < 4; ++fd)
                outp[row * 1024 + hh * 64 + fd * 16 + l16] =
                    (bf16_t)(o[fm][fd][e] * inv);
        }
}

// ---------------- launch ----------------
extern "C" void kernel_launch(void* const* d_in, const int* in_sizes, int n_in,
                              void* d_out, int out_size, void* d_ws, size_t ws_size,
                              hipStream_t stream)
{
    (void)in_sizes; (void)n_in; (void)out_size; (void)ws_size;
    const float* x      = (const float*)d_in[0];
    const float* wq     = (const float*)d_in[1];
    const float* wk     = (const float*)d_in[2];
    const float* wv     = (const float*)d_in[3];
    const float* w_proj = (const float*)d_in[4];
    const float* b_proj = (const float*)d_in[5];
    const float* w1     = (const float*)d_in[6];
    const float* b1     = (const float*)d_in[7];
    const float* w2     = (const float*)d_in[8];
    const float* b2     = (const float*)d_in[9];
    const float* g1  = (const float*)d_in[10]; const float* be1 = (const float*)d_in[11];
    const float* g2  = (const float*)d_in[12]; const float* be2 = (const float*)d_in[13];
    const float* g3  = (const float*)d_in[14]; const float* be3 = (const float*)d_in[15];

    char* ws = (char*)d_ws;
    bf16_t* wqkv  = (bf16_t*)(ws + 0);           //  6,291,456
    bf16_t* wproj = (bf16_t*)(ws + 6291456);     //  2,097,152
    bf16_t* w1t   = (bf16_t*)(ws + 8388608);     //  8,388,608
    bf16_t* w2t   = (bf16_t*)(ws + 16777216);    //  8,388,608
    bf16_t* h     = (bf16_t*)(ws + 25165824);    // 33,554,432 (LN1 out; attn out; start of u)
    bf16_t* qkv   = (bf16_t*)(ws + 58720256);    // 100,663,296 (V third unused)
    bf16_t* attn  = h;
    bf16_t* u     = h;                           // 134,217,728 over dead h+qkv
    bf16_t* y     = (bf16_t*)(ws + 159383552);   // 33,554,432 (vt before LN2; y after)
    bf16_t* vt    = y;
    float*  x2    = (float*)d_out;
    bf16_t* tbuf  = y;

    const int M = 16384;

    transpose_f32_bf16<<<dim3(16, 16), 256, 0, stream>>>(w_proj, wproj, 1024, 1024);
    transpose_f32_bf16<<<dim3(16, 64), 256, 0, stream>>>(w1, w1t, 4096, 1024);
    transpose_f32_bf16<<<dim3(64, 16), 256, 0, stream>>>(w2, w2t, 1024, 4096);
    pack_qkv_t<<<dim3(16, 48), 256, 0, stream>>>(wq, wk, wv, wqkv);

    // h = LN1(x)
    ln_fwd<<<M, 256, 0, stream>>>(x, g1, be1, h);
    // qkv = h @ Wqkv^T ; V columns written transposed into vt
    gemm_bt<4><<<dim3(64, 12), 512, 0, stream>>>(h, wqkv, qkv, nullptr, vt, M, 3072, 1024);
    // attention
    attn_kernel<<<1024, 256, 0, stream>>>(qkv, vt, attn);
    // x2 = x + attn @ Wproj^T + b_proj   -> d_out (f32)
    gemm_bt<1><<<dim3(64, 4), 512, 0, stream>>>(attn, wproj, x2, b_proj, x, M, 1024, 1024);
    // y = LN2(x2)   (overwrites vt, now dead)
    ln_fwd<<<M, 256, 0, stream>>>(x2, g2, be2, y);
    // u = relu(y @ W1^T + b1)
    gemm_bt<2><<<dim3(64, 16), 512, 0, stream>>>(y, w1t, u, b1, nullptr, M, 4096, 1024);
    // tbuf = y + (u @ W2^T + b2)
    gemm_bt<3><<<dim3(64, 4), 512, 0, stream>>>(u, w2t, tbuf, b2, y, M, 1024, 4096);
    // d_out = x2 + LN3(tbuf)
    ln3_kernel<<<M, 256, 0, stream>>>(tbuf, g3, be3, (float*)d_out, x2);
}

// Round 14
// 623.425 us; speedup vs baseline: 1.0389x; 1.0389x over previous
//
#include <hip/hip_runtime.h>

typedef __bf16 bf16_t;
typedef __bf16 bf16x8 __attribute__((ext_vector_type(8)));
typedef float f32x4 __attribute__((ext_vector_type(4)));

#define LN_EPS 1e-3f

__device__ __forceinline__ void gload_lds16(const void* g, void* l) {
    __builtin_amdgcn_global_load_lds(
        (__attribute__((address_space(1))) void*)(g),
        (__attribute__((address_space(3))) void*)(l), 16, 0, 0);
}

// ---------------- weight prep (LDS-tiled, coalesced both sides) ----------------
__global__ __launch_bounds__(256)
void transpose_f32_bf16(const float* __restrict__ in, bf16_t* __restrict__ outp,
                        int ldi, int ldo)
{
    __shared__ float tile[64][65];
    const int k0 = blockIdx.x * 64, n0 = blockIdx.y * 64;
    const int tid = threadIdx.x;
    const int r = tid >> 2;
    const int q = tid & 3;
    const float* src = in + (long)(k0 + r) * ldi + n0 + q * 16;
#pragma unroll
    for (int j = 0; j < 4; ++j) {
        float4 v = *(const float4*)(src + j * 4);
        tile[r][q * 16 + j * 4 + 0] = v.x;
        tile[r][q * 16 + j * 4 + 1] = v.y;
        tile[r][q * 16 + j * 4 + 2] = v.z;
        tile[r][q * 16 + j * 4 + 3] = v.w;
    }
    __syncthreads();
    union { bf16_t e[16]; uint4 u[2]; } pk;
#pragma unroll
    for (int j = 0; j < 16; ++j) pk.e[j] = (bf16_t)tile[q * 16 + j][r];
    bf16_t* dst = outp + (long)(n0 + r) * ldo + k0 + q * 16;
    *(uint4*)(dst)     = pk.u[0];
    *(uint4*)(dst + 8) = pk.u[1];
}

__global__ __launch_bounds__(256)
void pack_qkv_t(const float* __restrict__ wq, const float* __restrict__ wk,
                const float* __restrict__ wv, bf16_t* __restrict__ outp)
{
    __shared__ float tile[64][65];
    const int m   = blockIdx.y;           // 0..47
    const int sel = m >> 4, h = m & 15;
    const float* in = ((sel == 0) ? wq : (sel == 1) ? wk : wv) + (long)h * 65536;
    bf16_t* out = outp + ((long)sel * 1024 + h * 64) * 1024;
    const int k0 = blockIdx.x * 64;
    const int tid = threadIdx.x;
    const int r = tid >> 2;
    const int q = tid & 3;
    const float* src = in + (long)(k0 + r) * 64 + q * 16;
#pragma unroll
    for (int j = 0; j < 4; ++j) {
        float4 v = *(const float4*)(src + j * 4);
        tile[r][q * 16 + j * 4 + 0] = v.x;
        tile[r][q * 16 + j * 4 + 1] = v.y;
        tile[r][q * 16 + j * 4 + 2] = v.z;
        tile[r][q * 16 + j * 4 + 3] = v.w;
    }
    __syncthreads();
    union { bf16_t e[16]; uint4 u[2]; } pk;
#pragma unroll
    for (int j = 0; j < 16; ++j) pk.e[j] = (bf16_t)tile[q * 16 + j][r];
    bf16_t* dst = out + (long)r * 1024 + k0 + q * 16;
    *(uint4*)(dst)     = pk.u[0];
    *(uint4*)(dst + 8) = pk.u[1];
}

// ---------------- layernorm (f32 in -> bf16 LN out) ----------------
__global__ __launch_bounds__(256)
void ln_fwd(const float* __restrict__ in, const float* __restrict__ g,
            const float* __restrict__ be, bf16_t* __restrict__ outp)
{
    const long row = blockIdx.x;
    const int t = threadIdx.x;
    float4 v = ((const float4*)(in + row * 1024))[t];
    float s  = v.x + v.y + v.z + v.w;
    float sq = v.x * v.x + v.y * v.y + v.z * v.z + v.w * v.w;
#pragma unroll
    for (int off = 1; off < 64; off <<= 1) {
        s  += __shfl_xor(s, off);
        sq += __shfl_xor(sq, off);
    }
    __shared__ float red[8];
    if ((t & 63) == 0) { red[(t >> 6) * 2] = s; red[(t >> 6) * 2 + 1] = sq; }
    __syncthreads();
    s  = red[0] + red[2] + red[4] + red[6];
    sq = red[1] + red[3] + red[5] + red[7];
    float mean = s * 0.0009765625f;
    float var  = sq * 0.0009765625f - mean * mean;
    float rstd = rsqrtf(var + LN_EPS);
    float4 gv = ((const float4*)g)[t];
    float4 bv = ((const float4*)be)[t];
    union { bf16_t h[4]; uint2 u; } pk;
    pk.h[0] = (bf16_t)((v.x - mean) * rstd * gv.x + bv.x);
    pk.h[1] = (bf16_t)((v.y - mean) * rstd * gv.y + bv.y);
    pk.h[2] = (bf16_t)((v.z - mean) * rstd * gv.z + bv.z);
    pk.h[3] = (bf16_t)((v.w - mean) * rstd * gv.w + bv.w);
    *(uint2*)(outp + row * 1024 + t * 4) = pk.u;
}

// ---------------- final layernorm (bf16 in + f32 res -> f32 out) ----------------
__global__ __launch_bounds__(256)
void ln3_kernel(const bf16_t* __restrict__ in, const float* __restrict__ g,
                const float* __restrict__ be, float* outp, const float* res)
{
    const long row = blockIdx.x;
    const int t = threadIdx.x;
    union { uint2 u; bf16_t h[4]; } pk;
    pk.u = *(const uint2*)(in + row * 1024 + t * 4);
    float v0 = (float)pk.h[0], v1 = (float)pk.h[1], v2 = (float)pk.h[2], v3 = (float)pk.h[3];
    float s  = v0 + v1 + v2 + v3;
    float sq = v0 * v0 + v1 * v1 + v2 * v2 + v3 * v3;
#pragma unroll
    for (int off = 1; off < 64; off <<= 1) {
        s  += __shfl_xor(s, off);
        sq += __shfl_xor(sq, off);
    }
    __shared__ float red[8];
    if ((t & 63) == 0) { red[(t >> 6) * 2] = s; red[(t >> 6) * 2 + 1] = sq; }
    __syncthreads();
    s  = red[0] + red[2] + red[4] + red[6];
    sq = red[1] + red[3] + red[5] + red[7];
    float mean = s * 0.0009765625f;
    float var  = sq * 0.0009765625f - mean * mean;
    float rstd = rsqrtf(var + LN_EPS);
    float4 gv = ((const float4*)g)[t];
    float4 bv = ((const float4*)be)[t];
    float4 rv = ((const float4*)(res + row * 1024))[t];
    float4 ov;
    ov.x = rv.x + (v0 - mean) * rstd * gv.x + bv.x;
    ov.y = rv.y + (v1 - mean) * rstd * gv.y + bv.y;
    ov.z = rv.z + (v2 - mean) * rstd * gv.z + bv.z;
    ov.w = rv.w + (v3 - mean) * rstd * gv.w + bv.w;
    ((float4*)outp)[row * 256 + t] = ov;
}

// ---------------- GEMM: C[M,N] = A[M,K] * Bt[N,K]^T ----------------
// r11 golden schedule (measured best: FFN1 156us, 880 TF, MfmaUtil 37.7%):
// 256x256 tile, BK=64, 512 threads = 8 waves; 4 phases/K-tile.
// A (HBM-streamed) 3 LDS buffers, staged 2 K-tiles ahead (P1 h0, P3 h1);
// B (L2-hot weights) 2 buffers, staged 1 tile ahead at P1.
// P4: vmcnt(4) — queue A(c+1)h1|B(c+1)|A(c+2) (10) -> drains 6, leaves A(c+2).
// LDS = 5x32KB = 160KB (1 block/CU).
// MODE 0: bf16=acc; 1: f32=acc+bias+addf32; 2: bf16=relu(acc+bias);
// MODE 3: bf16=acc+bias+(float)addbf16 (outp may == addp);
// MODE 4: QKV mode — cols<2048 bf16=acc to outp; cols>=2048 (V) write V^T into
//         addp as vt[((b*16+h)*64+d)*256 + s] (packed 4-row uint2 stores).
template<int MODE>
__global__ __launch_bounds__(512, 2)
void gemm_bt(const bf16_t* __restrict__ Ap, const bf16_t* __restrict__ Bp,
             void* outp, const float* __restrict__ bias,
             const void* addp, int M, int N, int K)
{
    __shared__ __attribute__((aligned(16))) bf16_t As0[256 * 64];
    __shared__ __attribute__((aligned(16))) bf16_t As1[256 * 64];
    __shared__ __attribute__((aligned(16))) bf16_t As2[256 * 64];
    __shared__ __attribute__((aligned(16))) bf16_t Bs0[256 * 64];
    __shared__ __attribute__((aligned(16))) bf16_t Bs1[256 * 64];

    const int tid  = threadIdx.x;
    const int w    = tid >> 6, lane = tid & 63;
    const int l16  = lane & 15, lg = lane >> 4;
    const int wm   = w >> 2, wn = w & 3;
    const int srow = lane >> 3;
    const int sslot = lane & 7;

    const int gx  = gridDim.x;
    const int gy  = gridDim.y;
    const int nwg = gx * gy;
    const int bid = blockIdx.y * gx + blockIdx.x;
    const int cpx = nwg >> 3;
    const int sid = (bid & 7) * cpx + (bid >> 3);
    const long m0 = (long)(sid / gy) * 256;
    const long n0 = (long)(sid % gy) * 256;
    const int nkt = K >> 6;

    f32x4 acc[8][4] = {};
    bf16x8 a[4][2], b0[2][2], b1[2][2];

    auto STAGEH = [&](const bf16_t* src, long row0, int kt, bf16_t* dst, int h) {
#pragma unroll
        for (int i = 0; i < 2; ++i) {
            int r  = h * 128 + w * 16 + i * 8 + srow;
            int ss = sslot ^ (r & 7);
            gload_lds16(src + (row0 + r) * (long)K + (long)kt * 64 + ss * 8,
                        dst + (h * 128 + w * 16 + i * 8) * 64);
        }
    };

#define LDA_M(buf, mh) do {                                               \
    _Pragma("unroll") for (int j = 0; j < 4; ++j)                         \
    _Pragma("unroll") for (int kk = 0; kk < 2; ++kk) {                    \
        int r  = wm * 128 + (mh) * 64 + j * 16 + l16;                     \
        int ss = (kk * 4 + lg) ^ (r & 7);                                 \
        a[j][kk] = *(const bf16x8*)&buf[r * 64 + ss * 8];                 \
    } } while (0)

#define LDB_M(dst, buf, nh) do {                                          \
    _Pragma("unroll") for (int n = 0; n < 2; ++n)                         \
    _Pragma("unroll") for (int kk = 0; kk < 2; ++kk) {                    \
        int r  = wn * 64 + ((nh) * 2 + n) * 16 + l16;                     \
        int ss = (kk * 4 + lg) ^ (r & 7);                                 \
        dst[n][kk] = *(const bf16x8*)&buf[r * 64 + ss * 8];               \
    } } while (0)

#define MMA_M(bv, mh, nh) do {                                            \
    __builtin_amdgcn_s_setprio(1);                                        \
    _Pragma("unroll") for (int j = 0; j < 4; ++j)                         \
    _Pragma("unroll") for (int n = 0; n < 2; ++n)                         \
    _Pragma("unroll") for (int kk = 0; kk < 2; ++kk)                      \
        acc[(mh) * 4 + j][(nh) * 2 + n] =                                 \
            __builtin_amdgcn_mfma_f32_16x16x32_bf16(                      \
                a[j][kk], bv[n][kk], acc[(mh) * 4 + j][(nh) * 2 + n],     \
                0, 0, 0);                                                 \
    __builtin_amdgcn_s_setprio(0);                                        \
} while (0)

#define PRE_MFMA() do { __builtin_amdgcn_s_barrier();                     \
    asm volatile("s_waitcnt lgkmcnt(0)" ::: "memory");                    \
    __builtin_amdgcn_sched_barrier(0); } while (0)

    // ---- prologue: A(0)->As0, B(0)->Bs0, A(1)->As1, all landed ----
    STAGEH(Ap, m0, 0, As0, 0); STAGEH(Ap, m0, 0, As0, 1);
    STAGEH(Bp, n0, 0, Bs0, 0); STAGEH(Bp, n0, 0, Bs0, 1);
    if (nkt > 1) { STAGEH(Ap, m0, 1, As1, 0); STAGEH(Ap, m0, 1, As1, 1); }
    asm volatile("s_waitcnt vmcnt(0)" ::: "memory");
    __builtin_amdgcn_s_barrier();
    __builtin_amdgcn_sched_barrier(0);

    bf16_t *Ar = As0, *An1 = As1, *An2 = As2;
    bf16_t *Br = Bs0, *Bw = Bs1;

    for (int c = 0; c < nkt; ++c) {
        const bool pfa = (c + 2 < nkt);
        const bool pfb = (c + 1 < nkt);

        // P1
        LDA_M(Ar, 0); LDB_M(b0, Br, 0);
        if (pfb) { STAGEH(Bp, n0, c + 1, Bw, 0); STAGEH(Bp, n0, c + 1, Bw, 1); }
        if (pfa) STAGEH(Ap, m0, c + 2, An2, 0);
        PRE_MFMA(); MMA_M(b0, 0, 0); __builtin_amdgcn_s_barrier();
        // P2
        LDB_M(b1, Br, 1);
        PRE_MFMA(); MMA_M(b1, 0, 1); __builtin_amdgcn_s_barrier();
        // P3
        LDA_M(Ar, 1);
        if (pfa) STAGEH(Ap, m0, c + 2, An2, 1);
        PRE_MFMA(); MMA_M(b1, 1, 1); __builtin_amdgcn_s_barrier();
        // P4
        if (pfa) { asm volatile("s_waitcnt vmcnt(4)" ::: "memory"); }
        else     { asm volatile("s_waitcnt vmcnt(0)" ::: "memory"); }
        __builtin_amdgcn_s_barrier();
        __builtin_amdgcn_sched_barrier(0);
        MMA_M(b0, 1, 0); __builtin_amdgcn_s_barrier();

        bf16_t* t = Ar; Ar = An1; An1 = An2; An2 = t;
        t = Br; Br = Bw; Bw = t;
    }

    // ---- epilogue ----
#pragma unroll
    for (int fm = 0; fm < 8; ++fm) {
#pragma unroll
        for (int fn = 0; fn < 4; ++fn) {
            const long gcol = n0 + wn * 64 + fn * 16 + l16;
            float bv = 0.f;
            if (MODE != 0 && MODE != 4) bv = bias[gcol];
            const long grow0 = m0 + wm * 128 + fm * 16 + lg * 4;
            if (MODE == 4 && gcol >= 2048) {
                union { bf16_t h[4]; uint2 u; } pk;
#pragma unroll
                for (int e = 0; e < 4; ++e) pk.h[e] = (bf16_t)acc[fm][fn][e];
                const int hh = (int)(gcol >> 6) - 32;
                const int d  = (int)gcol & 63;
                const long bb = grow0 >> 8;
                const int s0  = (int)grow0 & 255;
                *(uint2*)((bf16_t*)addp + ((bb * 16 + hh) * 64 + d) * 256 + s0) = pk.u;
                continue;
            }
#pragma unroll
            for (int e = 0; e < 4; ++e) {
                const long grow = grow0 + e;
                float v = acc[fm][fn][e];
                if (MODE == 0 || MODE == 4) {
                    ((bf16_t*)outp)[grow * N + gcol] = (bf16_t)v;
                } else if (MODE == 1) {
                    v += bv + ((const float*)addp)[grow * N + gcol];
                    ((float*)outp)[grow * N + gcol] = v;
                } else if (MODE == 2) {
                    v += bv; v = v > 0.f ? v : 0.f;
                    ((bf16_t*)outp)[grow * N + gcol] = (bf16_t)v;
                } else {
                    v += bv + (float)((const bf16_t*)addp)[grow * N + gcol];
                    ((bf16_t*)outp)[grow * N + gcol] = (bf16_t)v;
                }
            }
        }
    }
#undef LDA_M
#undef LDB_M
#undef MMA_M
#undef PRE_MFMA
}

// ---------------- fused causal attention ----------------
// qkv: [B*T, 3072] bf16 (Q cols 0..1023, K cols 1024..2047)
// vt:  [B*H, 64, 256] bf16 (V^T, written by QKV GEMM MODE 4)
// 1 block per (b,h); 4 waves. One-shot staging: all 4 K/V tiles (64KB) staged
// once, single vmcnt(0)+barrier, then the causal triangle runs barrier-free
// (Ps is per-wave). Causal-balanced: fm block owns rows fm*64 + w*16 + [0,16).
// LDS 73KB -> 2 blocks/CU.
__global__ __launch_bounds__(256)
void attn_kernel(const bf16_t* __restrict__ qkv, const bf16_t* __restrict__ vt,
                 bf16_t* __restrict__ outp)
{
    __shared__ __attribute__((aligned(16))) bf16_t Kt[4][64 * 64];
    __shared__ __attribute__((aligned(16))) bf16_t Vt[4][64 * 64];
    __shared__ __attribute__((aligned(16))) bf16_t Ps[4][16 * 72];

    const int tid = threadIdx.x, w = tid >> 6, lane = tid & 63;
    const int l16 = lane & 15, lg = lane >> 4;
    const int b = blockIdx.x >> 4, hh = blockIdx.x & 15;
    const bf16_t* pq = qkv + (long)(b * 256) * 3072 + hh * 64;
    const bf16_t* pv = vt + (long)blockIdx.x * 64 * 256;
    const int sr8 = lane >> 3;
    const int sl  = lane & 7;

    // Q fragments: fm block rows = fm*64 + w*16 + l16
    bf16x8 qf[4][2];
#pragma unroll
    for (int fm = 0; fm < 4; ++fm)
#pragma unroll
        for (int kk = 0; kk < 2; ++kk)
            qf[fm][kk] = *(const bf16x8*)(pq + (long)(fm * 64 + w * 16 + l16) * 3072
                                          + kk * 32 + lg * 8);

    // one-shot stage of all K and V tiles
#pragma unroll
    for (int st = 0; st < 4; ++st)
#pragma unroll
        for (int i = 0; i < 2; ++i) {
            int r  = w * 16 + i * 8 + sr8;
            int ss = sl ^ (r & 7);
            gload_lds16(pq + (long)(st * 64 + r) * 3072 + 1024 + ss * 8,
                        &Kt[st][(w * 16 + i * 8) * 64]);
            gload_lds16(pv + (long)r * 256 + st * 64 + ss * 8,
                        &Vt[st][(w * 16 + i * 8) * 64]);
        }
    asm volatile("s_waitcnt vmcnt(0)" ::: "memory");
    __syncthreads();

    f32x4 o[4][4] = {};
    float mrun[4][4], lrun[4][4];
#pragma unroll
    for (int i = 0; i < 4; ++i)
#pragma unroll
        for (int j = 0; j < 4; ++j) { mrun[i][j] = -__builtin_inff(); lrun[i][j] = 0.f; }

#pragma unroll
    for (int st = 0; st < 4; ++st) {
        // S = Q K^T for fm >= st
        f32x4 s[4][4] = {};
#pragma unroll
        for (int ks = 0; ks < 2; ++ks) {
            bf16x8 kb[4];
#pragma unroll
            for (int fs = 0; fs < 4; ++fs)
                kb[fs] = *(const bf16x8*)&Kt[st][(fs * 16 + l16) * 64
                                                + ((ks * 4 + lg) ^ (l16 & 7)) * 8];
#pragma unroll
            for (int fm = 0; fm < 4; ++fm) {
                if (fm < st) continue;
#pragma unroll
                for (int fs = 0; fs < 4; ++fs)
                    s[fm][fs] = __builtin_amdgcn_mfma_f32_16x16x32_bf16(
                        qf[fm][ks], kb[fs], s[fm][fs], 0, 0, 0);
            }
        }

#pragma unroll
        for (int fm = 0; fm < 4; ++fm) {
            if (fm < st) continue;
#pragma unroll
            for (int fs = 0; fs < 4; ++fs)
#pragma unroll
                for (int e = 0; e < 4; ++e) {
                    float v = s[fm][fs][e] * 0.03125f;
                    if (st == fm && (fs * 16 + l16) > (w * 16 + lg * 4 + e))
                        v = -__builtin_inff();
                    s[fm][fs][e] = v;
                }
#pragma unroll
            for (int e = 0; e < 4; ++e) {
                float pm = fmaxf(fmaxf(s[fm][0][e], s[fm][1][e]),
                                 fmaxf(s[fm][2][e], s[fm][3][e]));
#pragma unroll
                for (int off = 1; off < 16; off <<= 1) pm = fmaxf(pm, __shfl_xor(pm, off));
                float mnew  = fmaxf(mrun[fm][e], pm);
                float alpha = __expf(mrun[fm][e] - mnew);
                float rs = 0.f;
#pragma unroll
                for (int fs = 0; fs < 4; ++fs) {
                    float p = __expf(s[fm][fs][e] - mnew);
                    s[fm][fs][e] = p;
                    rs += p;
                }
#pragma unroll
                for (int off = 1; off < 16; off <<= 1) rs += __shfl_xor(rs, off);
                lrun[fm][e] = lrun[fm][e] * alpha + rs;
                mrun[fm][e] = mnew;
#pragma unroll
                for (int fd = 0; fd < 4; ++fd) o[fm][fd][e] *= alpha;
            }
#pragma unroll
            for (int fs = 0; fs < 4; ++fs)
#pragma unroll
                for (int e = 0; e < 4; ++e)
                    Ps[w][(lg * 4 + e) * 72 + fs * 16 + l16] = (bf16_t)s[fm][fs][e];
            bf16x8 ap0 = *(const bf16x8*)&Ps[w][l16 * 72 + lg * 8];
            bf16x8 ap1 = *(const bf16x8*)&Ps[w][l16 * 72 + 32 + lg * 8];
#pragma unroll
            for (int fd = 0; fd < 4; ++fd) {
                bf16x8 vb0 = *(const bf16x8*)&Vt[st][(fd * 16 + l16) * 64
                                                    + ((lg) ^ (l16 & 7)) * 8];
                bf16x8 vb1 = *(const bf16x8*)&Vt[st][(fd * 16 + l16) * 64
                                                    + ((4 + lg) ^ (l16 & 7)) * 8];
                o[fm][fd] = __builtin_amdgcn_mfma_f32_16x16x32_bf16(ap0, vb0, o[fm][fd], 0, 0, 0);
                o[fm][fd] = __builtin_amdgcn_mfma_f32_16x16x32_bf16(ap1, vb1, o[fm][fd], 0, 0, 0);
            }
        }
    }

#pragma unroll
    for (int fm = 0; fm < 4; ++fm)
#pragma unroll
        for (int e = 0; e < 4; ++e) {
            float inv = 1.f / lrun[fm][e];
            long row = (long)b * 256 + fm * 64 + w * 16 + lg * 4 + e;
#pragma unroll
            for (int fd = 0; fd < 4; ++fd)
                outp[row * 1024 + hh * 64 + fd * 16 + l16] =
                    (bf16_t)(o[fm][fd][e] * inv);
        }
}

// ---------------- launch ----------------
extern "C" void kernel_launch(void* const* d_in, const int* in_sizes, int n_in,
                              void* d_out, int out_size, void* d_ws, size_t ws_size,
                              hipStream_t stream)
{
    (void)in_sizes; (void)n_in; (void)out_size; (void)ws_size;
    const float* x      = (const float*)d_in[0];
    const float* wq     = (const float*)d_in[1];
    const float* wk     = (const float*)d_in[2];
    const float* wv     = (const float*)d_in[3];
    const float* w_proj = (const float*)d_in[4];
    const float* b_proj = (const float*)d_in[5];
    const float* w1     = (const float*)d_in[6];
    const float* b1     = (const float*)d_in[7];
    const float* w2     = (const float*)d_in[8];
    const float* b2     = (const float*)d_in[9];
    const float* g1  = (const float*)d_in[10]; const float* be1 = (const float*)d_in[11];
    const float* g2  = (const float*)d_in[12]; const float* be2 = (const float*)d_in[13];
    const float* g3  = (const float*)d_in[14]; const float* be3 = (const float*)d_in[15];

    char* ws = (char*)d_ws;
    bf16_t* wqkv  = (bf16_t*)(ws + 0);           //  6,291,456
    bf16_t* wproj = (bf16_t*)(ws + 6291456);     //  2,097,152
    bf16_t* w1t   = (bf16_t*)(ws + 8388608);     //  8,388,608
    bf16_t* w2t   = (bf16_t*)(ws + 16777216);    //  8,388,608
    bf16_t* h     = (bf16_t*)(ws + 25165824);    // 33,554,432 (LN1 out; attn out; start of u)
    bf16_t* qkv   = (bf16_t*)(ws + 58720256);    // 100,663,296 (V third unused)
    bf16_t* attn  = h;
    bf16_t* u     = h;                           // 134,217,728 over dead h+qkv
    bf16_t* y     = (bf16_t*)(ws + 159383552);   // 33,554,432 (vt before LN2; y after)
    bf16_t* vt    = y;
    float*  x2    = (float*)d_out;
    bf16_t* tbuf  = y;

    const int M = 16384;

    transpose_f32_bf16<<<dim3(16, 16), 256, 0, stream>>>(w_proj, wproj, 1024, 1024);
    transpose_f32_bf16<<<dim3(16, 64), 256, 0, stream>>>(w1, w1t, 4096, 1024);
    transpose_f32_bf16<<<dim3(64, 16), 256, 0, stream>>>(w2, w2t, 1024, 4096);
    pack_qkv_t<<<dim3(16, 48), 256, 0, stream>>>(wq, wk, wv, wqkv);

    // h = LN1(x)
    ln_fwd<<<M, 256, 0, stream>>>(x, g1, be1, h);
    // qkv = h @ Wqkv^T ; V columns written transposed into vt
    gemm_bt<4><<<dim3(64, 12), 512, 0, stream>>>(h, wqkv, qkv, nullptr, vt, M, 3072, 1024);
    // attention
    attn_kernel<<<1024, 256, 0, stream>>>(qkv, vt, attn);
    // x2 = x + attn @ Wproj^T + b_proj   -> d_out (f32)
    gemm_bt<1><<<dim3(64, 4), 512, 0, stream>>>(attn, wproj, x2, b_proj, x, M, 1024, 1024);
    // y = LN2(x2)   (overwrites vt, now dead)
    ln_fwd<<<M, 256, 0, stream>>>(x2, g2, be2, y);
    // u = relu(y @ W1^T + b1)
    gemm_bt<2><<<dim3(64, 16), 512, 0, stream>>>(y, w1t, u, b1, nullptr, M, 4096, 1024);
    // tbuf = y + (u @ W2^T + b2)
    gemm_bt<3><<<dim3(64, 4), 512, 0, stream>>>(u, w2t, tbuf, b2, y, M, 1024, 4096);
    // d_out = x2 + LN3(tbuf)
    ln3_kernel<<<M, 256, 0, stream>>>(tbuf, g3, be3, (float*)d_out, x2);
}

// Round 15
// 601.682 us; speedup vs baseline: 1.0765x; 1.0361x over previous
//
#include <hip/hip_runtime.h>

typedef __bf16 bf16_t;
typedef __bf16 bf16x8 __attribute__((ext_vector_type(8)));
typedef float f32x4 __attribute__((ext_vector_type(4)));

#define LN_EPS 1e-3f

__device__ __forceinline__ void gload_lds16(const void* g, void* l) {
    __builtin_amdgcn_global_load_lds(
        (__attribute__((address_space(1))) void*)(g),
        (__attribute__((address_space(3))) void*)(l), 16, 0, 0);
}

// ---------------- unified weight prep ----------------
// 64x64 LDS-tiled f32->bf16 transpose: out[n*ldo+k] = (bf16)in[k*ldi+n]
__device__ __forceinline__ void tile_tr(const float* in, long ldi,
                                        bf16_t* out, long ldo,
                                        int k0, int n0, float* tile)
{
    const int tid = threadIdx.x;
    const int r = tid >> 2, q = tid & 3;
    const float* src = in + (long)(k0 + r) * ldi + n0 + q * 16;
#pragma unroll
    for (int j = 0; j < 4; ++j) {
        float4 v = *(const float4*)(src + j * 4);
        tile[r * 65 + q * 16 + j * 4 + 0] = v.x;
        tile[r * 65 + q * 16 + j * 4 + 1] = v.y;
        tile[r * 65 + q * 16 + j * 4 + 2] = v.z;
        tile[r * 65 + q * 16 + j * 4 + 3] = v.w;
    }
    __syncthreads();
    union { bf16_t e[16]; uint4 u[2]; } pk;
#pragma unroll
    for (int j = 0; j < 16; ++j) pk.e[j] = (bf16_t)tile[(q * 16 + j) * 65 + r];
    bf16_t* dst = out + (long)(n0 + r) * ldo + k0 + q * 16;
    *(uint4*)(dst)     = pk.u[0];
    *(uint4*)(dst + 8) = pk.u[1];
}

// one kernel for all weight prep. 3072 blocks:
// [0,256) wproj 16k x 16n; [256,1280) w1t 16k x 64n; [1280,2304) w2t 64k x 16n;
// [2304,3072) qkv 16k x 48 (sel,h) mats.
__global__ __launch_bounds__(256)
void prep_w(const float* __restrict__ wq, const float* __restrict__ wk,
            const float* __restrict__ wv, const float* __restrict__ w_proj,
            const float* __restrict__ w1, const float* __restrict__ w2,
            bf16_t* __restrict__ wqkv, bf16_t* __restrict__ wproj,
            bf16_t* __restrict__ w1t, bf16_t* __restrict__ w2t)
{
    __shared__ float tile[64 * 65];
    int id = blockIdx.x;
    if (id < 256) {
        tile_tr(w_proj, 1024, wproj, 1024, (id & 15) * 64, (id >> 4) * 64, tile);
    } else if (id < 1280) {
        int t = id - 256;
        tile_tr(w1, 4096, w1t, 1024, (t & 15) * 64, (t >> 4) * 64, tile);
    } else if (id < 2304) {
        int t = id - 1280;
        tile_tr(w2, 1024, w2t, 4096, (t & 63) * 64, (t >> 6) * 64, tile);
    } else {
        int t = id - 2304;
        int m = t >> 4, kx = t & 15;
        int sel = m >> 4, h = m & 15;
        const float* in = ((sel == 0) ? wq : (sel == 1) ? wk : wv) + (long)h * 65536;
        bf16_t* out = wqkv + ((long)sel * 1024 + h * 64) * 1024;
        tile_tr(in, 64, out, 1024, kx * 64, 0, tile);
    }
}

// ---------------- layernorm (f32 in -> bf16 LN out) ----------------
__global__ __launch_bounds__(256)
void ln_fwd(const float* __restrict__ in, const float* __restrict__ g,
            const float* __restrict__ be, bf16_t* __restrict__ outp)
{
    const long row = blockIdx.x;
    const int t = threadIdx.x;
    float4 v = ((const float4*)(in + row * 1024))[t];
    float s  = v.x + v.y + v.z + v.w;
    float sq = v.x * v.x + v.y * v.y + v.z * v.z + v.w * v.w;
#pragma unroll
    for (int off = 1; off < 64; off <<= 1) {
        s  += __shfl_xor(s, off);
        sq += __shfl_xor(sq, off);
    }
    __shared__ float red[8];
    if ((t & 63) == 0) { red[(t >> 6) * 2] = s; red[(t >> 6) * 2 + 1] = sq; }
    __syncthreads();
    s  = red[0] + red[2] + red[4] + red[6];
    sq = red[1] + red[3] + red[5] + red[7];
    float mean = s * 0.0009765625f;
    float var  = sq * 0.0009765625f - mean * mean;
    float rstd = rsqrtf(var + LN_EPS);
    float4 gv = ((const float4*)g)[t];
    float4 bv = ((const float4*)be)[t];
    union { bf16_t h[4]; uint2 u; } pk;
    pk.h[0] = (bf16_t)((v.x - mean) * rstd * gv.x + bv.x);
    pk.h[1] = (bf16_t)((v.y - mean) * rstd * gv.y + bv.y);
    pk.h[2] = (bf16_t)((v.z - mean) * rstd * gv.z + bv.z);
    pk.h[3] = (bf16_t)((v.w - mean) * rstd * gv.w + bv.w);
    *(uint2*)(outp + row * 1024 + t * 4) = pk.u;
}

// ---------------- layernorm (bf16 in -> bf16 LN out) ----------------
__global__ __launch_bounds__(256)
void ln_fwd_b(const bf16_t* __restrict__ in, const float* __restrict__ g,
              const float* __restrict__ be, bf16_t* __restrict__ outp)
{
    const long row = blockIdx.x;
    const int t = threadIdx.x;
    union { uint2 u; bf16_t h[4]; } pin;
    pin.u = *(const uint2*)(in + row * 1024 + t * 4);
    float v0 = (float)pin.h[0], v1 = (float)pin.h[1],
          v2 = (float)pin.h[2], v3 = (float)pin.h[3];
    float s  = v0 + v1 + v2 + v3;
    float sq = v0 * v0 + v1 * v1 + v2 * v2 + v3 * v3;
#pragma unroll
    for (int off = 1; off < 64; off <<= 1) {
        s  += __shfl_xor(s, off);
        sq += __shfl_xor(sq, off);
    }
    __shared__ float red[8];
    if ((t & 63) == 0) { red[(t >> 6) * 2] = s; red[(t >> 6) * 2 + 1] = sq; }
    __syncthreads();
    s  = red[0] + red[2] + red[4] + red[6];
    sq = red[1] + red[3] + red[5] + red[7];
    float mean = s * 0.0009765625f;
    float var  = sq * 0.0009765625f - mean * mean;
    float rstd = rsqrtf(var + LN_EPS);
    float4 gv = ((const float4*)g)[t];
    float4 bv = ((const float4*)be)[t];
    union { bf16_t h[4]; uint2 u; } pk;
    pk.h[0] = (bf16_t)((v0 - mean) * rstd * gv.x + bv.x);
    pk.h[1] = (bf16_t)((v1 - mean) * rstd * gv.y + bv.y);
    pk.h[2] = (bf16_t)((v2 - mean) * rstd * gv.z + bv.z);
    pk.h[3] = (bf16_t)((v3 - mean) * rstd * gv.w + bv.w);
    *(uint2*)(outp + row * 1024 + t * 4) = pk.u;
}

// ---------------- final layernorm (bf16 in + res -> f32 out) ----------------
// RESB=0: res f32 (may == outp); RESB=1: res bf16
template<int RESB>
__global__ __launch_bounds__(256)
void ln3_kernel(const bf16_t* __restrict__ in, const float* __restrict__ g,
                const float* __restrict__ be, float* outp, const void* res)
{
    const long row = blockIdx.x;
    const int t = threadIdx.x;
    union { uint2 u; bf16_t h[4]; } pk;
    pk.u = *(const uint2*)(in + row * 1024 + t * 4);
    float v0 = (float)pk.h[0], v1 = (float)pk.h[1], v2 = (float)pk.h[2], v3 = (float)pk.h[3];
    float s  = v0 + v1 + v2 + v3;
    float sq = v0 * v0 + v1 * v1 + v2 * v2 + v3 * v3;
#pragma unroll
    for (int off = 1; off < 64; off <<= 1) {
        s  += __shfl_xor(s, off);
        sq += __shfl_xor(sq, off);
    }
    __shared__ float red[8];
    if ((t & 63) == 0) { red[(t >> 6) * 2] = s; red[(t >> 6) * 2 + 1] = sq; }
    __syncthreads();
    s  = red[0] + red[2] + red[4] + red[6];
    sq = red[1] + red[3] + red[5] + red[7];
    float mean = s * 0.0009765625f;
    float var  = sq * 0.0009765625f - mean * mean;
    float rstd = rsqrtf(var + LN_EPS);
    float4 gv = ((const float4*)g)[t];
    float4 bv = ((const float4*)be)[t];
    float r0, r1, r2, r3;
    if (RESB == 0) {
        float4 rv = ((const float4*)((const float*)res + row * 1024))[t];
        r0 = rv.x; r1 = rv.y; r2 = rv.z; r3 = rv.w;
    } else {
        union { uint2 u; bf16_t h[4]; } pr;
        pr.u = *(const uint2*)((const bf16_t*)res + row * 1024 + t * 4);
        r0 = (float)pr.h[0]; r1 = (float)pr.h[1];
        r2 = (float)pr.h[2]; r3 = (float)pr.h[3];
    }
    float4 ov;
    ov.x = r0 + (v0 - mean) * rstd * gv.x + bv.x;
    ov.y = r1 + (v1 - mean) * rstd * gv.y + bv.y;
    ov.z = r2 + (v2 - mean) * rstd * gv.z + bv.z;
    ov.w = r3 + (v3 - mean) * rstd * gv.w + bv.w;
    ((float4*)outp)[row * 256 + t] = ov;
}

// ---------------- GEMM: C[M,N] = A[M,K] * Bt[N,K]^T ----------------
// r11 golden schedule + A-h1 moved P3->P2 (one more phase of HBM cover).
// Steady-state ledger (per-thread vm ops): entering iter c: A(c+1) x4 in
// flight. P1: +B(c+1)x4 +A(c+2)h0 x2; P2: +A(c+2)h1 x2 (=12). P4 vmcnt(4):
// drains A(c+1)+B(c+1) exactly, leaves A(c+2) x4. An2-h1 write at P2 is safe:
// its LDS range was last read at c-1's P3 (barriered).
// MODE 0: bf16=acc; 1: f32=acc+bias+addf32; 2: bf16=relu(acc+bias);
// MODE 3: bf16=acc+bias+(float)addbf16 (outp may == addp);
// MODE 4: QKV: cols<2048 bf16=acc; cols>=2048 (V) -> V^T into addp;
// MODE 5: bf16=acc+bias+addf32.
template<int MODE>
__global__ __launch_bounds__(512, 2)
void gemm_bt(const bf16_t* __restrict__ Ap, const bf16_t* __restrict__ Bp,
             void* outp, const float* __restrict__ bias,
             const void* addp, int M, int N, int K)
{
    __shared__ __attribute__((aligned(16))) bf16_t As0[256 * 64];
    __shared__ __attribute__((aligned(16))) bf16_t As1[256 * 64];
    __shared__ __attribute__((aligned(16))) bf16_t As2[256 * 64];
    __shared__ __attribute__((aligned(16))) bf16_t Bs0[256 * 64];
    __shared__ __attribute__((aligned(16))) bf16_t Bs1[256 * 64];

    const int tid  = threadIdx.x;
    const int w    = tid >> 6, lane = tid & 63;
    const int l16  = lane & 15, lg = lane >> 4;
    const int wm   = w >> 2, wn = w & 3;
    const int srow = lane >> 3;
    const int sslot = lane & 7;

    const int gx  = gridDim.x;
    const int gy  = gridDim.y;
    const int nwg = gx * gy;
    const int bid = blockIdx.y * gx + blockIdx.x;
    const int cpx = nwg >> 3;
    const int sid = (bid & 7) * cpx + (bid >> 3);
    const long m0 = (long)(sid / gy) * 256;
    const long n0 = (long)(sid % gy) * 256;
    const int nkt = K >> 6;

    f32x4 acc[8][4] = {};
    bf16x8 a[4][2], b0[2][2], b1[2][2];

    auto STAGEH = [&](const bf16_t* src, long row0, int kt, bf16_t* dst, int h) {
#pragma unroll
        for (int i = 0; i < 2; ++i) {
            int r  = h * 128 + w * 16 + i * 8 + srow;
            int ss = sslot ^ (r & 7);
            gload_lds16(src + (row0 + r) * (long)K + (long)kt * 64 + ss * 8,
                        dst + (h * 128 + w * 16 + i * 8) * 64);
        }
    };

#define LDA_M(buf, mh) do {                                               \
    _Pragma("unroll") for (int j = 0; j < 4; ++j)                         \
    _Pragma("unroll") for (int kk = 0; kk < 2; ++kk) {                    \
        int r  = wm * 128 + (mh) * 64 + j * 16 + l16;                     \
        int ss = (kk * 4 + lg) ^ (r & 7);                                 \
        a[j][kk] = *(const bf16x8*)&buf[r * 64 + ss * 8];                 \
    } } while (0)

#define LDB_M(dst, buf, nh) do {                                          \
    _Pragma("unroll") for (int n = 0; n < 2; ++n)                         \
    _Pragma("unroll") for (int kk = 0; kk < 2; ++kk) {                    \
        int r  = wn * 64 + ((nh) * 2 + n) * 16 + l16;                     \
        int ss = (kk * 4 + lg) ^ (r & 7);                                 \
        dst[n][kk] = *(const bf16x8*)&buf[r * 64 + ss * 8];               \
    } } while (0)

#define MMA_M(bv, mh, nh) do {                                            \
    __builtin_amdgcn_s_setprio(1);                                        \
    _Pragma("unroll") for (int j = 0; j < 4; ++j)                         \
    _Pragma("unroll") for (int n = 0; n < 2; ++n)                         \
    _Pragma("unroll") for (int kk = 0; kk < 2; ++kk)                      \
        acc[(mh) * 4 + j][(nh) * 2 + n] =                                 \
            __builtin_amdgcn_mfma_f32_16x16x32_bf16(                      \
                a[j][kk], bv[n][kk], acc[(mh) * 4 + j][(nh) * 2 + n],     \
                0, 0, 0);                                                 \
    __builtin_amdgcn_s_setprio(0);                                        \
} while (0)

#define PRE_MFMA() do { __builtin_amdgcn_s_barrier();                     \
    asm volatile("s_waitcnt lgkmcnt(0)" ::: "memory");                    \
    __builtin_amdgcn_sched_barrier(0); } while (0)

    // ---- prologue: A(0)->As0, B(0)->Bs0, A(1)->As1, all landed ----
    STAGEH(Ap, m0, 0, As0, 0); STAGEH(Ap, m0, 0, As0, 1);
    STAGEH(Bp, n0, 0, Bs0, 0); STAGEH(Bp, n0, 0, Bs0, 1);
    if (nkt > 1) { STAGEH(Ap, m0, 1, As1, 0); STAGEH(Ap, m0, 1, As1, 1); }
    asm volatile("s_waitcnt vmcnt(0)" ::: "memory");
    __builtin_amdgcn_s_barrier();
    __builtin_amdgcn_sched_barrier(0);

    bf16_t *Ar = As0, *An1 = As1, *An2 = As2;
    bf16_t *Br = Bs0, *Bw = Bs1;

    for (int c = 0; c < nkt; ++c) {
        const bool pfa = (c + 2 < nkt);
        const bool pfb = (c + 1 < nkt);

        // P1
        LDA_M(Ar, 0); LDB_M(b0, Br, 0);
        if (pfb) { STAGEH(Bp, n0, c + 1, Bw, 0); STAGEH(Bp, n0, c + 1, Bw, 1); }
        if (pfa) STAGEH(Ap, m0, c + 2, An2, 0);
        PRE_MFMA(); MMA_M(b0, 0, 0); __builtin_amdgcn_s_barrier();
        // P2
        LDB_M(b1, Br, 1);
        if (pfa) STAGEH(Ap, m0, c + 2, An2, 1);
        PRE_MFMA(); MMA_M(b1, 0, 1); __builtin_amdgcn_s_barrier();
        // P3
        LDA_M(Ar, 1);
        PRE_MFMA(); MMA_M(b1, 1, 1); __builtin_amdgcn_s_barrier();
        // P4
        if (pfa) { asm volatile("s_waitcnt vmcnt(4)" ::: "memory"); }
        else     { asm volatile("s_waitcnt vmcnt(0)" ::: "memory"); }
        __builtin_amdgcn_s_barrier();
        __builtin_amdgcn_sched_barrier(0);
        MMA_M(b0, 1, 0); __builtin_amdgcn_s_barrier();

        bf16_t* t = Ar; Ar = An1; An1 = An2; An2 = t;
        t = Br; Br = Bw; Bw = t;
    }

    // ---- epilogue ----
#pragma unroll
    for (int fm = 0; fm < 8; ++fm) {
#pragma unroll
        for (int fn = 0; fn < 4; ++fn) {
            const long gcol = n0 + wn * 64 + fn * 16 + l16;
            float bv = 0.f;
            if (MODE != 0 && MODE != 4) bv = bias[gcol];
            const long grow0 = m0 + wm * 128 + fm * 16 + lg * 4;
            if (MODE == 4 && gcol >= 2048) {
                union { bf16_t h[4]; uint2 u; } pk;
#pragma unroll
                for (int e = 0; e < 4; ++e) pk.h[e] = (bf16_t)acc[fm][fn][e];
                const int hh = (int)(gcol >> 6) - 32;
                const int d  = (int)gcol & 63;
                const long bb = grow0 >> 8;
                const int s0  = (int)grow0 & 255;
                *(uint2*)((bf16_t*)addp + ((bb * 16 + hh) * 64 + d) * 256 + s0) = pk.u;
                continue;
            }
#pragma unroll
            for (int e = 0; e < 4; ++e) {
                const long grow = grow0 + e;
                float v = acc[fm][fn][e];
                if (MODE == 0 || MODE == 4) {
                    ((bf16_t*)outp)[grow * N + gcol] = (bf16_t)v;
                } else if (MODE == 1) {
                    v += bv + ((const float*)addp)[grow * N + gcol];
                    ((float*)outp)[grow * N + gcol] = v;
                } else if (MODE == 2) {
                    v += bv; v = v > 0.f ? v : 0.f;
                    ((bf16_t*)outp)[grow * N + gcol] = (bf16_t)v;
                } else if (MODE == 3) {
                    v += bv + (float)((const bf16_t*)addp)[grow * N + gcol];
                    ((bf16_t*)outp)[grow * N + gcol] = (bf16_t)v;
                } else { // MODE 5
                    v += bv + ((const float*)addp)[grow * N + gcol];
                    ((bf16_t*)outp)[grow * N + gcol] = (bf16_t)v;
                }
            }
        }
    }
#undef LDA_M
#undef LDB_M
#undef MMA_M
#undef PRE_MFMA
}

// ---------------- fused causal attention ----------------
// qkv: [B*T, 3072] bf16 (Q cols 0..1023, K cols 1024..2047)
// vt:  [B*H, 64, 256] bf16 (V^T, written by QKV GEMM MODE 4)
// 1 block per (b,h); 4 waves; one-shot staging (64KB), barrier-free triangle;
// causal-balanced: fm block owns rows fm*64 + w*16 + [0,16). LDS 73KB.
__global__ __launch_bounds__(256)
void attn_kernel(const bf16_t* __restrict__ qkv, const bf16_t* __restrict__ vt,
                 bf16_t* __restrict__ outp)
{
    __shared__ __attribute__((aligned(16))) bf16_t Kt[4][64 * 64];
    __shared__ __attribute__((aligned(16))) bf16_t Vt[4][64 * 64];
    __shared__ __attribute__((aligned(16))) bf16_t Ps[4][16 * 72];

    const int tid = threadIdx.x, w = tid >> 6, lane = tid & 63;
    const int l16 = lane & 15, lg = lane >> 4;
    const int b = blockIdx.x >> 4, hh = blockIdx.x & 15;
    const bf16_t* pq = qkv + (long)(b * 256) * 3072 + hh * 64;
    const bf16_t* pv = vt + (long)blockIdx.x * 64 * 256;
    const int sr8 = lane >> 3;
    const int sl  = lane & 7;

    bf16x8 qf[4][2];
#pragma unroll
    for (int fm = 0; fm < 4; ++fm)
#pragma unroll
        for (int kk = 0; kk < 2; ++kk)
            qf[fm][kk] = *(const bf16x8*)(pq + (long)(fm * 64 + w * 16 + l16) * 3072
                                          + kk * 32 + lg * 8);

#pragma unroll
    for (int st = 0; st < 4; ++st)
#pragma unroll
        for (int i = 0; i < 2; ++i) {
            int r  = w * 16 + i * 8 + sr8;
            int ss = sl ^ (r & 7);
            gload_lds16(pq + (long)(st * 64 + r) * 3072 + 1024 + ss * 8,
                        &Kt[st][(w * 16 + i * 8) * 64]);
            gload_lds16(pv + (long)r * 256 + st * 64 + ss * 8,
                        &Vt[st][(w * 16 + i * 8) * 64]);
        }
    asm volatile("s_waitcnt vmcnt(0)" ::: "memory");
    __syncthreads();

    f32x4 o[4][4] = {};
    float mrun[4][4], lrun[4][4];
#pragma unroll
    for (int i = 0; i < 4; ++i)
#pragma unroll
        for (int j = 0; j < 4; ++j) { mrun[i][j] = -__builtin_inff(); lrun[i][j] = 0.f; }

#pragma unroll
    for (int st = 0; st < 4; ++st) {
        f32x4 s[4][4] = {};
#pragma unroll
        for (int ks = 0; ks < 2; ++ks) {
            bf16x8 kb[4];
#pragma unroll
            for (int fs = 0; fs < 4; ++fs)
                kb[fs] = *(const bf16x8*)&Kt[st][(fs * 16 + l16) * 64
                                                + ((ks * 4 + lg) ^ (l16 & 7)) * 8];
#pragma unroll
            for (int fm = 0; fm < 4; ++fm) {
                if (fm < st) continue;
#pragma unroll
                for (int fs = 0; fs < 4; ++fs)
                    s[fm][fs] = __builtin_amdgcn_mfma_f32_16x16x32_bf16(
                        qf[fm][ks], kb[fs], s[fm][fs], 0, 0, 0);
            }
        }

#pragma unroll
        for (int fm = 0; fm < 4; ++fm) {
            if (fm < st) continue;
#pragma unroll
            for (int fs = 0; fs < 4; ++fs)
#pragma unroll
                for (int e = 0; e < 4; ++e) {
                    float v = s[fm][fs][e] * 0.03125f;
                    if (st == fm && (fs * 16 + l16) > (w * 16 + lg * 4 + e))
                        v = -__builtin_inff();
                    s[fm][fs][e] = v;
                }
#pragma unroll
            for (int e = 0; e < 4; ++e) {
                float pm = fmaxf(fmaxf(s[fm][0][e], s[fm][1][e]),
                                 fmaxf(s[fm][2][e], s[fm][3][e]));
#pragma unroll
                for (int off = 1; off < 16; off <<= 1) pm = fmaxf(pm, __shfl_xor(pm, off));
                float mnew  = fmaxf(mrun[fm][e], pm);
                float alpha = __expf(mrun[fm][e] - mnew);
                float rs = 0.f;
#pragma unroll
                for (int fs = 0; fs < 4; ++fs) {
                    float p = __expf(s[fm][fs][e] - mnew);
                    s[fm][fs][e] = p;
                    rs += p;
                }
#pragma unroll
                for (int off = 1; off < 16; off <<= 1) rs += __shfl_xor(rs, off);
                lrun[fm][e] = lrun[fm][e] * alpha + rs;
                mrun[fm][e] = mnew;
#pragma unroll
                for (int fd = 0; fd < 4; ++fd) o[fm][fd][e] *= alpha;
            }
#pragma unroll
            for (int fs = 0; fs < 4; ++fs)
#pragma unroll
                for (int e = 0; e < 4; ++e)
                    Ps[w][(lg * 4 + e) * 72 + fs * 16 + l16] = (bf16_t)s[fm][fs][e];
            bf16x8 ap0 = *(const bf16x8*)&Ps[w][l16 * 72 + lg * 8];
            bf16x8 ap1 = *(const bf16x8*)&Ps[w][l16 * 72 + 32 + lg * 8];
#pragma unroll
            for (int fd = 0; fd < 4; ++fd) {
                bf16x8 vb0 = *(const bf16x8*)&Vt[st][(fd * 16 + l16) * 64
                                                    + ((lg) ^ (l16 & 7)) * 8];
                bf16x8 vb1 = *(const bf16x8*)&Vt[st][(fd * 16 + l16) * 64
                                                    + ((4 + lg) ^ (l16 & 7)) * 8];
                o[fm][fd] = __builtin_amdgcn_mfma_f32_16x16x32_bf16(ap0, vb0, o[fm][fd], 0, 0, 0);
                o[fm][fd] = __builtin_amdgcn_mfma_f32_16x16x32_bf16(ap1, vb1, o[fm][fd], 0, 0, 0);
            }
        }
    }

#pragma unroll
    for (int fm = 0; fm < 4; ++fm)
#pragma unroll
        for (int e = 0; e < 4; ++e) {
            float inv = 1.f / lrun[fm][e];
            long row = (long)b * 256 + fm * 64 + w * 16 + lg * 4 + e;
#pragma unroll
            for (int fd = 0; fd < 4; ++fd)
                outp[row * 1024 + hh * 64 + fd * 16 + l16] =
                    (bf16_t)(o[fm][fd][e] * inv);
        }
}

// ---------------- launch ----------------
extern "C" void kernel_launch(void* const* d_in, const int* in_sizes, int n_in,
                              void* d_out, int out_size, void* d_ws, size_t ws_size,
                              hipStream_t stream)
{
    (void)in_sizes; (void)n_in; (void)out_size;
    const float* x      = (const float*)d_in[0];
    const float* wq     = (const float*)d_in[1];
    const float* wk     = (const float*)d_in[2];
    const float* wv     = (const float*)d_in[3];
    const float* w_proj = (const float*)d_in[4];
    const float* b_proj = (const float*)d_in[5];
    const float* w1     = (const float*)d_in[6];
    const float* b1     = (const float*)d_in[7];
    const float* w2     = (const float*)d_in[8];
    const float* b2     = (const float*)d_in[9];
    const float* g1  = (const float*)d_in[10]; const float* be1 = (const float*)d_in[11];
    const float* g2  = (const float*)d_in[12]; const float* be2 = (const float*)d_in[13];
    const float* g3  = (const float*)d_in[14]; const float* be3 = (const float*)d_in[15];

    char* ws = (char*)d_ws;
    bf16_t* wqkv  = (bf16_t*)(ws + 0);           //  6,291,456
    bf16_t* wproj = (bf16_t*)(ws + 6291456);     //  2,097,152
    bf16_t* w1t   = (bf16_t*)(ws + 8388608);     //  8,388,608
    bf16_t* w2t   = (bf16_t*)(ws + 16777216);    //  8,388,608
    bf16_t* h     = (bf16_t*)(ws + 25165824);    // 33,554,432 (LN1 out; attn out; start of u)
    bf16_t* qkv   = (bf16_t*)(ws + 58720256);    // 100,663,296 (V third unused)
    bf16_t* attn  = h;
    bf16_t* u     = h;                           // 134,217,728 over dead h+qkv
    bf16_t* y     = (bf16_t*)(ws + 159383552);   // 33,554,432 (vt before LN2; y after)
    bf16_t* vt    = y;
    bf16_t* tbuf  = y;
    bf16_t* x2b   = (bf16_t*)(ws + 192937984);   // 33,554,432 (only if ws permits)
    const bool big = ws_size >= (size_t)226492416;

    const int M = 16384;

    prep_w<<<3072, 256, 0, stream>>>(wq, wk, wv, w_proj, w1, w2,
                                     wqkv, wproj, w1t, w2t);

    // h = LN1(x)
    ln_fwd<<<M, 256, 0, stream>>>(x, g1, be1, h);
    // qkv = h @ Wqkv^T ; V columns written transposed into vt
    gemm_bt<4><<<dim3(64, 12), 512, 0, stream>>>(h, wqkv, qkv, nullptr, vt, M, 3072, 1024);
    // attention
    attn_kernel<<<1024, 256, 0, stream>>>(qkv, vt, attn);

    if (big) {
        // x2b (bf16) = x + attn @ Wproj^T + b_proj
        gemm_bt<5><<<dim3(64, 4), 512, 0, stream>>>(attn, wproj, x2b, b_proj, x, M, 1024, 1024);
        // y = LN2(x2b)
        ln_fwd_b<<<M, 256, 0, stream>>>(x2b, g2, be2, y);
        // u = relu(y @ W1^T + b1)
        gemm_bt<2><<<dim3(64, 16), 512, 0, stream>>>(y, w1t, u, b1, nullptr, M, 4096, 1024);
        // tbuf = y + (u @ W2^T + b2)
        gemm_bt<3><<<dim3(64, 4), 512, 0, stream>>>(u, w2t, tbuf, b2, y, M, 1024, 4096);
        // d_out = x2b + LN3(tbuf)
        ln3_kernel<1><<<M, 256, 0, stream>>>(tbuf, g3, be3, (float*)d_out, x2b);
    } else {
        float* x2 = (float*)d_out;
        gemm_bt<1><<<dim3(64, 4), 512, 0, stream>>>(attn, wproj, x2, b_proj, x, M, 1024, 1024);
        ln_fwd<<<M, 256, 0, stream>>>(x2, g2, be2, y);
        gemm_bt<2><<<dim3(64, 16), 512, 0, stream>>>(y, w1t, u, b1, nullptr, M, 4096, 1024);
        gemm_bt<3><<<dim3(64, 4), 512, 0, stream>>>(u, w2t, tbuf, b2, y, M, 1024, 4096);
        ln3_kernel<0><<<M, 256, 0, stream>>>(tbuf, g3, be3, (float*)d_out, x2);
    }
}

// Round 16
// 590.569 us; speedup vs baseline: 1.0967x; 1.0188x over previous
//
#include <hip/hip_runtime.h>

typedef __bf16 bf16_t;
typedef __bf16 bf16x8 __attribute__((ext_vector_type(8)));
typedef float f32x4 __attribute__((ext_vector_type(4)));

#define LN_EPS 1e-3f

__device__ __forceinline__ void gload_lds16(const void* g, void* l) {
    __builtin_amdgcn_global_load_lds(
        (__attribute__((address_space(1))) void*)(g),
        (__attribute__((address_space(3))) void*)(l), 16, 0, 0);
}

// ---------------- unified weight prep ----------------
__device__ __forceinline__ void tile_tr(const float* in, long ldi,
                                        bf16_t* out, long ldo,
                                        int k0, int n0, float* tile)
{
    const int tid = threadIdx.x;
    const int r = tid >> 2, q = tid & 3;
    const float* src = in + (long)(k0 + r) * ldi + n0 + q * 16;
#pragma unroll
    for (int j = 0; j < 4; ++j) {
        float4 v = *(const float4*)(src + j * 4);
        tile[r * 65 + q * 16 + j * 4 + 0] = v.x;
        tile[r * 65 + q * 16 + j * 4 + 1] = v.y;
        tile[r * 65 + q * 16 + j * 4 + 2] = v.z;
        tile[r * 65 + q * 16 + j * 4 + 3] = v.w;
    }
    __syncthreads();
    union { bf16_t e[16]; uint4 u[2]; } pk;
#pragma unroll
    for (int j = 0; j < 16; ++j) pk.e[j] = (bf16_t)tile[(q * 16 + j) * 65 + r];
    bf16_t* dst = out + (long)(n0 + r) * ldo + k0 + q * 16;
    *(uint4*)(dst)     = pk.u[0];
    *(uint4*)(dst + 8) = pk.u[1];
}

__global__ __launch_bounds__(256)
void prep_w(const float* __restrict__ wq, const float* __restrict__ wk,
            const float* __restrict__ wv, const float* __restrict__ w_proj,
            const float* __restrict__ w1, const float* __restrict__ w2,
            bf16_t* __restrict__ wqkv, bf16_t* __restrict__ wproj,
            bf16_t* __restrict__ w1t, bf16_t* __restrict__ w2t)
{
    __shared__ float tile[64 * 65];
    int id = blockIdx.x;
    if (id < 256) {
        tile_tr(w_proj, 1024, wproj, 1024, (id & 15) * 64, (id >> 4) * 64, tile);
    } else if (id < 1280) {
        int t = id - 256;
        tile_tr(w1, 4096, w1t, 1024, (t & 15) * 64, (t >> 4) * 64, tile);
    } else if (id < 2304) {
        int t = id - 1280;
        tile_tr(w2, 1024, w2t, 4096, (t & 63) * 64, (t >> 6) * 64, tile);
    } else {
        int t = id - 2304;
        int m = t >> 4, kx = t & 15;
        int sel = m >> 4, h = m & 15;
        const float* in = ((sel == 0) ? wq : (sel == 1) ? wk : wv) + (long)h * 65536;
        bf16_t* out = wqkv + ((long)sel * 1024 + h * 64) * 1024;
        tile_tr(in, 64, out, 1024, kx * 64, 0, tile);
    }
}

// ---------------- layernorm (f32 in -> bf16 LN out) ----------------
__global__ __launch_bounds__(256)
void ln_fwd(const float* __restrict__ in, const float* __restrict__ g,
            const float* __restrict__ be, bf16_t* __restrict__ outp)
{
    const long row = blockIdx.x;
    const int t = threadIdx.x;
    float4 v = ((const float4*)(in + row * 1024))[t];
    float s  = v.x + v.y + v.z + v.w;
    float sq = v.x * v.x + v.y * v.y + v.z * v.z + v.w * v.w;
#pragma unroll
    for (int off = 1; off < 64; off <<= 1) {
        s  += __shfl_xor(s, off);
        sq += __shfl_xor(sq, off);
    }
    __shared__ float red[8];
    if ((t & 63) == 0) { red[(t >> 6) * 2] = s; red[(t >> 6) * 2 + 1] = sq; }
    __syncthreads();
    s  = red[0] + red[2] + red[4] + red[6];
    sq = red[1] + red[3] + red[5] + red[7];
    float mean = s * 0.0009765625f;
    float var  = sq * 0.0009765625f - mean * mean;
    float rstd = rsqrtf(var + LN_EPS);
    float4 gv = ((const float4*)g)[t];
    float4 bv = ((const float4*)be)[t];
    union { bf16_t h[4]; uint2 u; } pk;
    pk.h[0] = (bf16_t)((v.x - mean) * rstd * gv.x + bv.x);
    pk.h[1] = (bf16_t)((v.y - mean) * rstd * gv.y + bv.y);
    pk.h[2] = (bf16_t)((v.z - mean) * rstd * gv.z + bv.z);
    pk.h[3] = (bf16_t)((v.w - mean) * rstd * gv.w + bv.w);
    *(uint2*)(outp + row * 1024 + t * 4) = pk.u;
}

// ---------------- layernorm (bf16 in -> bf16 LN out) ----------------
__global__ __launch_bounds__(256)
void ln_fwd_b(const bf16_t* __restrict__ in, const float* __restrict__ g,
              const float* __restrict__ be, bf16_t* __restrict__ outp)
{
    const long row = blockIdx.x;
    const int t = threadIdx.x;
    union { uint2 u; bf16_t h[4]; } pin;
    pin.u = *(const uint2*)(in + row * 1024 + t * 4);
    float v0 = (float)pin.h[0], v1 = (float)pin.h[1],
          v2 = (float)pin.h[2], v3 = (float)pin.h[3];
    float s  = v0 + v1 + v2 + v3;
    float sq = v0 * v0 + v1 * v1 + v2 * v2 + v3 * v3;
#pragma unroll
    for (int off = 1; off < 64; off <<= 1) {
        s  += __shfl_xor(s, off);
        sq += __shfl_xor(sq, off);
    }
    __shared__ float red[8];
    if ((t & 63) == 0) { red[(t >> 6) * 2] = s; red[(t >> 6) * 2 + 1] = sq; }
    __syncthreads();
    s  = red[0] + red[2] + red[4] + red[6];
    sq = red[1] + red[3] + red[5] + red[7];
    float mean = s * 0.0009765625f;
    float var  = sq * 0.0009765625f - mean * mean;
    float rstd = rsqrtf(var + LN_EPS);
    float4 gv = ((const float4*)g)[t];
    float4 bv = ((const float4*)be)[t];
    union { bf16_t h[4]; uint2 u; } pk;
    pk.h[0] = (bf16_t)((v0 - mean) * rstd * gv.x + bv.x);
    pk.h[1] = (bf16_t)((v1 - mean) * rstd * gv.y + bv.y);
    pk.h[2] = (bf16_t)((v2 - mean) * rstd * gv.z + bv.z);
    pk.h[3] = (bf16_t)((v3 - mean) * rstd * gv.w + bv.w);
    *(uint2*)(outp + row * 1024 + t * 4) = pk.u;
}

// ---------------- final layernorm (bf16 in + res -> f32 out) ----------------
template<int RESB>
__global__ __launch_bounds__(256)
void ln3_kernel(const bf16_t* __restrict__ in, const float* __restrict__ g,
                const float* __restrict__ be, float* outp, const void* res)
{
    const long row = blockIdx.x;
    const int t = threadIdx.x;
    union { uint2 u; bf16_t h[4]; } pk;
    pk.u = *(const uint2*)(in + row * 1024 + t * 4);
    float v0 = (float)pk.h[0], v1 = (float)pk.h[1], v2 = (float)pk.h[2], v3 = (float)pk.h[3];
    float s  = v0 + v1 + v2 + v3;
    float sq = v0 * v0 + v1 * v1 + v2 * v2 + v3 * v3;
#pragma unroll
    for (int off = 1; off < 64; off <<= 1) {
        s  += __shfl_xor(s, off);
        sq += __shfl_xor(sq, off);
    }
    __shared__ float red[8];
    if ((t & 63) == 0) { red[(t >> 6) * 2] = s; red[(t >> 6) * 2 + 1] = sq; }
    __syncthreads();
    s  = red[0] + red[2] + red[4] + red[6];
    sq = red[1] + red[3] + red[5] + red[7];
    float mean = s * 0.0009765625f;
    float var  = sq * 0.0009765625f - mean * mean;
    float rstd = rsqrtf(var + LN_EPS);
    float4 gv = ((const float4*)g)[t];
    float4 bv = ((const float4*)be)[t];
    float r0, r1, r2, r3;
    if (RESB == 0) {
        float4 rv = ((const float4*)((const float*)res + row * 1024))[t];
        r0 = rv.x; r1 = rv.y; r2 = rv.z; r3 = rv.w;
    } else {
        union { uint2 u; bf16_t h[4]; } pr;
        pr.u = *(const uint2*)((const bf16_t*)res + row * 1024 + t * 4);
        r0 = (float)pr.h[0]; r1 = (float)pr.h[1];
        r2 = (float)pr.h[2]; r3 = (float)pr.h[3];
    }
    float4 ov;
    ov.x = r0 + (v0 - mean) * rstd * gv.x + bv.x;
    ov.y = r1 + (v1 - mean) * rstd * gv.y + bv.y;
    ov.z = r2 + (v2 - mean) * rstd * gv.z + bv.z;
    ov.w = r3 + (v3 - mean) * rstd * gv.w + bv.w;
    ((float4*)outp)[row * 256 + t] = ov;
}

// ---------------- GEMM: C[M,N] = A[M,K] * Bt[N,K]^T ----------------
// 2-PHASE schedule (halved barrier count vs r14's 4-phase):
// Phase A: ds a(mh0) 8 + b0,b1 8 (16 x b128); stage B(c+1) + A(c+2)h0;
//          barrier; lgkmcnt(0); 32 MFMA (mh0 x all fn); barrier.
// Phase B: ds a(mh1) 8; stage A(c+2)h1; barrier; lgkmcnt(0); 32 MFMA (mh1);
//          vmcnt(4); barrier.
// Invariant: entering iter c, A(c+1)x4 in flight; iter adds B(c+1)x4 +
// A(c+2)x4; vmcnt(4) drains A(c+1)+B(c+1), leaves A(c+2). A 3-buf / B 2-buf,
// LDS 160KB. Write-after-read: An2 region = Ar two iters ago (barriered);
// Bw last read in c-1 Phase A.
// MODE 0: bf16=acc; 1: f32=acc+bias+addf32; 2: bf16=relu(acc+bias);
// MODE 3: bf16=acc+bias+(float)addbf16 (outp may == addp);
// MODE 4: QKV: cols<2048 bf16=acc; cols>=2048 (V) -> V^T into addp;
// MODE 5: bf16=acc+bias+addf32.
template<int MODE>
__global__ __launch_bounds__(512, 2)
void gemm_bt(const bf16_t* __restrict__ Ap, const bf16_t* __restrict__ Bp,
             void* outp, const float* __restrict__ bias,
             const void* addp, int M, int N, int K)
{
    __shared__ __attribute__((aligned(16))) bf16_t As0[256 * 64];
    __shared__ __attribute__((aligned(16))) bf16_t As1[256 * 64];
    __shared__ __attribute__((aligned(16))) bf16_t As2[256 * 64];
    __shared__ __attribute__((aligned(16))) bf16_t Bs0[256 * 64];
    __shared__ __attribute__((aligned(16))) bf16_t Bs1[256 * 64];

    const int tid  = threadIdx.x;
    const int w    = tid >> 6, lane = tid & 63;
    const int l16  = lane & 15, lg = lane >> 4;
    const int wm   = w >> 2, wn = w & 3;
    const int srow = lane >> 3;
    const int sslot = lane & 7;

    const int gx  = gridDim.x;
    const int gy  = gridDim.y;
    const int nwg = gx * gy;
    const int bid = blockIdx.y * gx + blockIdx.x;
    const int cpx = nwg >> 3;
    const int sid = (bid & 7) * cpx + (bid >> 3);
    const long m0 = (long)(sid / gy) * 256;
    const long n0 = (long)(sid % gy) * 256;
    const int nkt = K >> 6;

    f32x4 acc[8][4] = {};
    bf16x8 a[4][2], b0[2][2], b1[2][2];

    auto STAGEH = [&](const bf16_t* src, long row0, int kt, bf16_t* dst, int h) {
#pragma unroll
        for (int i = 0; i < 2; ++i) {
            int r  = h * 128 + w * 16 + i * 8 + srow;
            int ss = sslot ^ (r & 7);
            gload_lds16(src + (row0 + r) * (long)K + (long)kt * 64 + ss * 8,
                        dst + (h * 128 + w * 16 + i * 8) * 64);
        }
    };

#define LDA_M(buf, mh) do {                                               \
    _Pragma("unroll") for (int j = 0; j < 4; ++j)                         \
    _Pragma("unroll") for (int kk = 0; kk < 2; ++kk) {                    \
        int r  = wm * 128 + (mh) * 64 + j * 16 + l16;                     \
        int ss = (kk * 4 + lg) ^ (r & 7);                                 \
        a[j][kk] = *(const bf16x8*)&buf[r * 64 + ss * 8];                 \
    } } while (0)

#define LDB_M(dst, buf, nh) do {                                          \
    _Pragma("unroll") for (int n = 0; n < 2; ++n)                         \
    _Pragma("unroll") for (int kk = 0; kk < 2; ++kk) {                    \
        int r  = wn * 64 + ((nh) * 2 + n) * 16 + l16;                     \
        int ss = (kk * 4 + lg) ^ (r & 7);                                 \
        dst[n][kk] = *(const bf16x8*)&buf[r * 64 + ss * 8];               \
    } } while (0)

#define MMA2_M(mh) do {                                                   \
    __builtin_amdgcn_s_setprio(1);                                        \
    _Pragma("unroll") for (int j = 0; j < 4; ++j)                         \
    _Pragma("unroll") for (int n = 0; n < 2; ++n)                         \
    _Pragma("unroll") for (int kk = 0; kk < 2; ++kk) {                    \
        acc[(mh) * 4 + j][n] = __builtin_amdgcn_mfma_f32_16x16x32_bf16(   \
            a[j][kk], b0[n][kk], acc[(mh) * 4 + j][n], 0, 0, 0);          \
        acc[(mh) * 4 + j][2 + n] = __builtin_amdgcn_mfma_f32_16x16x32_bf16(\
            a[j][kk], b1[n][kk], acc[(mh) * 4 + j][2 + n], 0, 0, 0);      \
    }                                                                     \
    __builtin_amdgcn_s_setprio(0);                                        \
} while (0)

#define PRE_MFMA() do { __builtin_amdgcn_s_barrier();                     \
    asm volatile("s_waitcnt lgkmcnt(0)" ::: "memory");                    \
    __builtin_amdgcn_sched_barrier(0); } while (0)

    // ---- prologue: A(0)->As0, B(0)->Bs0, A(1)->As1, all landed ----
    STAGEH(Ap, m0, 0, As0, 0); STAGEH(Ap, m0, 0, As0, 1);
    STAGEH(Bp, n0, 0, Bs0, 0); STAGEH(Bp, n0, 0, Bs0, 1);
    if (nkt > 1) { STAGEH(Ap, m0, 1, As1, 0); STAGEH(Ap, m0, 1, As1, 1); }
    asm volatile("s_waitcnt vmcnt(0)" ::: "memory");
    __builtin_amdgcn_s_barrier();
    __builtin_amdgcn_sched_barrier(0);

    bf16_t *Ar = As0, *An1 = As1, *An2 = As2;
    bf16_t *Br = Bs0, *Bw = Bs1;

    for (int c = 0; c < nkt; ++c) {
        const bool pfa = (c + 2 < nkt);
        const bool pfb = (c + 1 < nkt);

        // Phase A
        LDA_M(Ar, 0); LDB_M(b0, Br, 0); LDB_M(b1, Br, 1);
        if (pfb) { STAGEH(Bp, n0, c + 1, Bw, 0); STAGEH(Bp, n0, c + 1, Bw, 1); }
        if (pfa) STAGEH(Ap, m0, c + 2, An2, 0);
        PRE_MFMA();
        MMA2_M(0);
        __builtin_amdgcn_s_barrier();

        // Phase B
        LDA_M(Ar, 1);
        if (pfa) STAGEH(Ap, m0, c + 2, An2, 1);
        PRE_MFMA();
        MMA2_M(1);
        if (pfa) { asm volatile("s_waitcnt vmcnt(4)" ::: "memory"); }
        else     { asm volatile("s_waitcnt vmcnt(0)" ::: "memory"); }
        __builtin_amdgcn_s_barrier();
        __builtin_amdgcn_sched_barrier(0);

        bf16_t* t = Ar; Ar = An1; An1 = An2; An2 = t;
        t = Br; Br = Bw; Bw = t;
    }

    // ---- epilogue ----
#pragma unroll
    for (int fm = 0; fm < 8; ++fm) {
#pragma unroll
        for (int fn = 0; fn < 4; ++fn) {
            const long gcol = n0 + wn * 64 + fn * 16 + l16;
            float bv = 0.f;
            if (MODE != 0 && MODE != 4) bv = bias[gcol];
            const long grow0 = m0 + wm * 128 + fm * 16 + lg * 4;
            if (MODE == 4 && gcol >= 2048) {
                union { bf16_t h[4]; uint2 u; } pk;
#pragma unroll
                for (int e = 0; e < 4; ++e) pk.h[e] = (bf16_t)acc[fm][fn][e];
                const int hh = (int)(gcol >> 6) - 32;
                const int d  = (int)gcol & 63;
                const long bb = grow0 >> 8;
                const int s0  = (int)grow0 & 255;
                *(uint2*)((bf16_t*)addp + ((bb * 16 + hh) * 64 + d) * 256 + s0) = pk.u;
                continue;
            }
#pragma unroll
            for (int e = 0; e < 4; ++e) {
                const long grow = grow0 + e;
                float v = acc[fm][fn][e];
                if (MODE == 0 || MODE == 4) {
                    ((bf16_t*)outp)[grow * N + gcol] = (bf16_t)v;
                } else if (MODE == 1) {
                    v += bv + ((const float*)addp)[grow * N + gcol];
                    ((float*)outp)[grow * N + gcol] = v;
                } else if (MODE == 2) {
                    v += bv; v = v > 0.f ? v : 0.f;
                    ((bf16_t*)outp)[grow * N + gcol] = (bf16_t)v;
                } else if (MODE == 3) {
                    v += bv + (float)((const bf16_t*)addp)[grow * N + gcol];
                    ((bf16_t*)outp)[grow * N + gcol] = (bf16_t)v;
                } else { // MODE 5
                    v += bv + ((const float*)addp)[grow * N + gcol];
                    ((bf16_t*)outp)[grow * N + gcol] = (bf16_t)v;
                }
            }
        }
    }
#undef LDA_M
#undef LDB_M
#undef MMA2_M
#undef PRE_MFMA
}

// ---------------- fused causal attention ----------------
// qkv: [B*T, 3072] bf16 (Q cols 0..1023, K cols 1024..2047)
// vt:  [B*H, 64, 256] bf16 (V^T, written by QKV GEMM MODE 4)
// 1 block per (b,h); 4 waves; one-shot staging (64KB), barrier-free triangle;
// causal-balanced: fm block owns rows fm*64 + w*16 + [0,16). LDS 73KB.
__global__ __launch_bounds__(256)
void attn_kernel(const bf16_t* __restrict__ qkv, const bf16_t* __restrict__ vt,
                 bf16_t* __restrict__ outp)
{
    __shared__ __attribute__((aligned(16))) bf16_t Kt[4][64 * 64];
    __shared__ __attribute__((aligned(16))) bf16_t Vt[4][64 * 64];
    __shared__ __attribute__((aligned(16))) bf16_t Ps[4][16 * 72];

    const int tid = threadIdx.x, w = tid >> 6, lane = tid & 63;
    const int l16 = lane & 15, lg = lane >> 4;
    const int b = blockIdx.x >> 4, hh = blockIdx.x & 15;
    const bf16_t* pq = qkv + (long)(b * 256) * 3072 + hh * 64;
    const bf16_t* pv = vt + (long)blockIdx.x * 64 * 256;
    const int sr8 = lane >> 3;
    const int sl  = lane & 7;

    bf16x8 qf[4][2];
#pragma unroll
    for (int fm = 0; fm < 4; ++fm)
#pragma unroll
        for (int kk = 0; kk < 2; ++kk)
            qf[fm][kk] = *(const bf16x8*)(pq + (long)(fm * 64 + w * 16 + l16) * 3072
                                          + kk * 32 + lg * 8);

#pragma unroll
    for (int st = 0; st < 4; ++st)
#pragma unroll
        for (int i = 0; i < 2; ++i) {
            int r  = w * 16 + i * 8 + sr8;
            int ss = sl ^ (r & 7);
            gload_lds16(pq + (long)(st * 64 + r) * 3072 + 1024 + ss * 8,
                        &Kt[st][(w * 16 + i * 8) * 64]);
            gload_lds16(pv + (long)r * 256 + st * 64 + ss * 8,
                        &Vt[st][(w * 16 + i * 8) * 64]);
        }
    asm volatile("s_waitcnt vmcnt(0)" ::: "memory");
    __syncthreads();

    f32x4 o[4][4] = {};
    float mrun[4][4], lrun[4][4];
#pragma unroll
    for (int i = 0; i < 4; ++i)
#pragma unroll
        for (int j = 0; j < 4; ++j) { mrun[i][j] = -__builtin_inff(); lrun[i][j] = 0.f; }

#pragma unroll
    for (int st = 0; st < 4; ++st) {
        f32x4 s[4][4] = {};
#pragma unroll
        for (int ks = 0; ks < 2; ++ks) {
            bf16x8 kb[4];
#pragma unroll
            for (int fs = 0; fs < 4; ++fs)
                kb[fs] = *(const bf16x8*)&Kt[st][(fs * 16 + l16) * 64
                                                + ((ks * 4 + lg) ^ (l16 & 7)) * 8];
#pragma unroll
            for (int fm = 0; fm < 4; ++fm) {
                if (fm < st) continue;
#pragma unroll
                for (int fs = 0; fs < 4; ++fs)
                    s[fm][fs] = __builtin_amdgcn_mfma_f32_16x16x32_bf16(
                        qf[fm][ks], kb[fs], s[fm][fs], 0, 0, 0);
            }
        }

#pragma unroll
        for (int fm = 0; fm < 4; ++fm) {
            if (fm < st) continue;
#pragma unroll
            for (int fs = 0; fs < 4; ++fs)
#pragma unroll
                for (int e = 0; e < 4; ++e) {
                    float v = s[fm][fs][e] * 0.03125f;
                    if (st == fm && (fs * 16 + l16) > (w * 16 + lg * 4 + e))
                        v = -__builtin_inff();
                    s[fm][fs][e] = v;
                }
#pragma unroll
            for (int e = 0; e < 4; ++e) {
                float pm = fmaxf(fmaxf(s[fm][0][e], s[fm][1][e]),
                                 fmaxf(s[fm][2][e], s[fm][3][e]));
#pragma unroll
                for (int off = 1; off < 16; off <<= 1) pm = fmaxf(pm, __shfl_xor(pm, off));
                float mnew  = fmaxf(mrun[fm][e], pm);
                float alpha = __expf(mrun[fm][e] - mnew);
                float rs = 0.f;
#pragma unroll
                for (int fs = 0; fs < 4; ++fs) {
                    float p = __expf(s[fm][fs][e] - mnew);
                    s[fm][fs][e] = p;
                    rs += p;
                }
#pragma unroll
                for (int off = 1; off < 16; off <<= 1) rs += __shfl_xor(rs, off);
                lrun[fm][e] = lrun[fm][e] * alpha + rs;
                mrun[fm][e] = mnew;
#pragma unroll
                for (int fd = 0; fd < 4; ++fd) o[fm][fd][e] *= alpha;
            }
#pragma unroll
            for (int fs = 0; fs < 4; ++fs)
#pragma unroll
                for (int e = 0; e < 4; ++e)
                    Ps[w][(lg * 4 + e) * 72 + fs * 16 + l16] = (bf16_t)s[fm][fs][e];
            bf16x8 ap0 = *(const bf16x8*)&Ps[w][l16 * 72 + lg * 8];
            bf16x8 ap1 = *(const bf16x8*)&Ps[w][l16 * 72 + 32 + lg * 8];
#pragma unroll
            for (int fd = 0; fd < 4; ++fd) {
                bf16x8 vb0 = *(const bf16x8*)&Vt[st][(fd * 16 + l16) * 64
                                                    + ((lg) ^ (l16 & 7)) * 8];
                bf16x8 vb1 = *(const bf16x8*)&Vt[st][(fd * 16 + l16) * 64
                                                    + ((4 + lg) ^ (l16 & 7)) * 8];
                o[fm][fd] = __builtin_amdgcn_mfma_f32_16x16x32_bf16(ap0, vb0, o[fm][fd], 0, 0, 0);
                o[fm][fd] = __builtin_amdgcn_mfma_f32_16x16x32_bf16(ap1, vb1, o[fm][fd], 0, 0, 0);
            }
        }
    }

#pragma unroll
    for (int fm = 0; fm < 4; ++fm)
#pragma unroll
        for (int e = 0; e < 4; ++e) {
            float inv = 1.f / lrun[fm][e];
            long row = (long)b * 256 + fm * 64 + w * 16 + lg * 4 + e;
#pragma unroll
            for (int fd = 0; fd < 4; ++fd)
                outp[row * 1024 + hh * 64 + fd * 16 + l16] =
                    (bf16_t)(o[fm][fd][e] * inv);
        }
}

// ---------------- launch ----------------
extern "C" void kernel_launch(void* const* d_in, const int* in_sizes, int n_in,
                              void* d_out, int out_size, void* d_ws, size_t ws_size,
                              hipStream_t stream)
{
    (void)in_sizes; (void)n_in; (void)out_size;
    const float* x      = (const float*)d_in[0];
    const float* wq     = (const float*)d_in[1];
    const float* wk     = (const float*)d_in[2];
    const float* wv     = (const float*)d_in[3];
    const float* w_proj = (const float*)d_in[4];
    const float* b_proj = (const float*)d_in[5];
    const float* w1     = (const float*)d_in[6];
    const float* b1     = (const float*)d_in[7];
    const float* w2     = (const float*)d_in[8];
    const float* b2     = (const float*)d_in[9];
    const float* g1  = (const float*)d_in[10]; const float* be1 = (const float*)d_in[11];
    const float* g2  = (const float*)d_in[12]; const float* be2 = (const float*)d_in[13];
    const float* g3  = (const float*)d_in[14]; const float* be3 = (const float*)d_in[15];

    char* ws = (char*)d_ws;
    bf16_t* wqkv  = (bf16_t*)(ws + 0);           //  6,291,456
    bf16_t* wproj = (bf16_t*)(ws + 6291456);     //  2,097,152
    bf16_t* w1t   = (bf16_t*)(ws + 8388608);     //  8,388,608
    bf16_t* w2t   = (bf16_t*)(ws + 16777216);    //  8,388,608
    bf16_t* h     = (bf16_t*)(ws + 25165824);    // 33,554,432 (LN1 out; attn out; start of u)
    bf16_t* qkv   = (bf16_t*)(ws + 58720256);    // 100,663,296 (V third unused)
    bf16_t* attn  = h;
    bf16_t* u     = h;                           // 134,217,728 over dead h+qkv
    bf16_t* y     = (bf16_t*)(ws + 159383552);   // 33,554,432 (vt before LN2; y after)
    bf16_t* vt    = y;
    bf16_t* tbuf  = y;
    bf16_t* x2b   = (bf16_t*)(ws + 192937984);   // 33,554,432 (only if ws permits)
    const bool big = ws_size >= (size_t)226492416;

    const int M = 16384;

    prep_w<<<3072, 256, 0, stream>>>(wq, wk, wv, w_proj, w1, w2,
                                     wqkv, wproj, w1t, w2t);

    // h = LN1(x)
    ln_fwd<<<M, 256, 0, stream>>>(x, g1, be1, h);
    // qkv = h @ Wqkv^T ; V columns written transposed into vt
    gemm_bt<4><<<dim3(64, 12), 512, 0, stream>>>(h, wqkv, qkv, nullptr, vt, M, 3072, 1024);
    // attention
    attn_kernel<<<1024, 256, 0, stream>>>(qkv, vt, attn);

    if (big) {
        gemm_bt<5><<<dim3(64, 4), 512, 0, stream>>>(attn, wproj, x2b, b_proj, x, M, 1024, 1024);
        ln_fwd_b<<<M, 256, 0, stream>>>(x2b, g2, be2, y);
        gemm_bt<2><<<dim3(64, 16), 512, 0, stream>>>(y, w1t, u, b1, nullptr, M, 4096, 1024);
        gemm_bt<3><<<dim3(64, 4), 512, 0, stream>>>(u, w2t, tbuf, b2, y, M, 1024, 4096);
        ln3_kernel<1><<<M, 256, 0, stream>>>(tbuf, g3, be3, (float*)d_out, x2b);
    } else {
        float* x2 = (float*)d_out;
        gemm_bt<1><<<dim3(64, 4), 512, 0, stream>>>(attn, wproj, x2, b_proj, x, M, 1024, 1024);
        ln_fwd<<<M, 256, 0, stream>>>(x2, g2, be2, y);
        gemm_bt<2><<<dim3(64, 16), 512, 0, stream>>>(y, w1t, u, b1, nullptr, M, 4096, 1024);
        gemm_bt<3><<<dim3(64, 4), 512, 0, stream>>>(u, w2t, tbuf, b2, y, M, 1024, 4096);
        ln3_kernel<0><<<M, 256, 0, stream>>>(tbuf, g3, be3, (float*)d_out, x2);
    }
}